// Round 1
// baseline (982.990 us; speedup 1.0000x reference)
//
#include <hip/hip_runtime.h>
#include <math.h>

#define NN 512
#define NN2 (NN*NN)
#define NB 32
#define NM 64
#define FLTMAX 3.402823466e38f

__device__ __forceinline__ float sigm(float x) { return 1.0f / (1.0f + expf(-x)); }

// ---------------- row sums of squares (with sigmoid for X matrices) -------------
__global__ __launch_bounds__(256) void sq_kernel(const float* __restrict__ model,
                                                 const float* __restrict__ labels,
                                                 float* __restrict__ sq) {
  int gw = blockIdx.x * 4 + (threadIdx.x >> 6);   // global wave id = matrix*512 + row
  int lane = threadIdx.x & 63;
  int m = gw >> 9;
  int row = gw & 511;
  if (m >= NM) return;
  const float* src = (m & 1) ? labels + (size_t)(m >> 1) * NN2
                             : model + (size_t)(m >> 1) * NN2;
  bool sg = !(m & 1);
  const float4* rp = (const float4*)(src + (size_t)row * NN);
  float s = 0.f;
  #pragma unroll
  for (int c = 0; c < 2; ++c) {
    float4 v = rp[lane + c * 64];
    if (sg) { v.x = sigm(v.x); v.y = sigm(v.y); v.z = sigm(v.z); v.w = sigm(v.w); }
    s += v.x * v.x + v.y * v.y + v.z * v.z + v.w * v.w;
  }
  #pragma unroll
  for (int off = 32; off > 0; off >>= 1) s += __shfl_down(s, off);
  if (lane == 0) sq[(size_t)m * NN + row] = s;
}

// ---------------- distance matrix via fp32 tiled GEMM (G = X X^T) ---------------
__global__ __launch_bounds__(256) void gemm_dist(const float* __restrict__ model,
                                                 const float* __restrict__ labels,
                                                 const float* __restrict__ sq,
                                                 float* __restrict__ Dreg, int m0) {
  __shared__ float As[32][68];
  __shared__ float Bs[32][68];
  int mL = blockIdx.z;
  int m = m0 + mL;
  const float* src = (m & 1) ? labels + (size_t)(m >> 1) * NN2
                             : model + (size_t)(m >> 1) * NN2;
  bool sg = !(m & 1);
  int by = blockIdx.y, bx = blockIdx.x;
  int tid = threadIdx.x;
  int lr = tid >> 2;             // 0..63: row within tile panel
  int kq = (tid & 3) * 8;        // 0,8,16,24: k-offset of this thread's 8 elements
  int ty = tid >> 4, tx = tid & 15;
  float acc[4][4] = {};
  const float* arow = src + (size_t)(by * 64 + lr) * NN + kq;
  const float* brow = src + (size_t)(bx * 64 + lr) * NN + kq;

  for (int k0 = 0; k0 < NN; k0 += 32) {
    float4 a0 = *(const float4*)(arow + k0);
    float4 a1 = *(const float4*)(arow + k0 + 4);
    float4 b0 = *(const float4*)(brow + k0);
    float4 b1 = *(const float4*)(brow + k0 + 4);
    if (sg) {
      a0.x = sigm(a0.x); a0.y = sigm(a0.y); a0.z = sigm(a0.z); a0.w = sigm(a0.w);
      a1.x = sigm(a1.x); a1.y = sigm(a1.y); a1.z = sigm(a1.z); a1.w = sigm(a1.w);
      b0.x = sigm(b0.x); b0.y = sigm(b0.y); b0.z = sigm(b0.z); b0.w = sigm(b0.w);
      b1.x = sigm(b1.x); b1.y = sigm(b1.y); b1.z = sigm(b1.z); b1.w = sigm(b1.w);
    }
    As[kq + 0][lr] = a0.x; As[kq + 1][lr] = a0.y; As[kq + 2][lr] = a0.z; As[kq + 3][lr] = a0.w;
    As[kq + 4][lr] = a1.x; As[kq + 5][lr] = a1.y; As[kq + 6][lr] = a1.z; As[kq + 7][lr] = a1.w;
    Bs[kq + 0][lr] = b0.x; Bs[kq + 1][lr] = b0.y; Bs[kq + 2][lr] = b0.z; Bs[kq + 3][lr] = b0.w;
    Bs[kq + 4][lr] = b1.x; Bs[kq + 5][lr] = b1.y; Bs[kq + 6][lr] = b1.z; Bs[kq + 7][lr] = b1.w;
    __syncthreads();
    #pragma unroll
    for (int kk = 0; kk < 32; ++kk) {
      const float4 a4 = *(const float4*)&As[kk][ty * 4];
      const float4 b4 = *(const float4*)&Bs[kk][tx * 4];
      const float av[4] = {a4.x, a4.y, a4.z, a4.w};
      const float bv[4] = {b4.x, b4.y, b4.z, b4.w};
      #pragma unroll
      for (int r = 0; r < 4; ++r)
        #pragma unroll
        for (int c = 0; c < 4; ++c)
          acc[r][c] = fmaf(av[r], bv[c], acc[r][c]);
    }
    __syncthreads();
  }

  const float* sqm = sq + (size_t)m * NN;
  float sqi[4], sqj[4];
  #pragma unroll
  for (int r = 0; r < 4; ++r) sqi[r] = sqm[by * 64 + ty * 4 + r];
  #pragma unroll
  for (int c = 0; c < 4; ++c) sqj[c] = sqm[bx * 64 + tx * 4 + c];
  float* drow = Dreg + (size_t)mL * NN2 + (size_t)(by * 64 + ty * 4) * NN + bx * 64 + tx * 4;
  #pragma unroll
  for (int r = 0; r < 4; ++r) {
    float4 o;
    o.x = sqrtf(fmaxf(sqi[r] + sqj[0] - 2.f * acc[r][0], 0.f));
    o.y = sqrtf(fmaxf(sqi[r] + sqj[1] - 2.f * acc[r][1], 0.f));
    o.z = sqrtf(fmaxf(sqi[r] + sqj[2] - 2.f * acc[r][2], 0.f));
    o.w = sqrtf(fmaxf(sqi[r] + sqj[3] - 2.f * acc[r][3], 0.f));
    *(float4*)(drow + (size_t)r * NN) = o;
  }
}

// ---------------- per-matrix max (2-stage) --------------------------------------
__global__ __launch_bounds__(256) void max_kernel(const float* __restrict__ Dreg,
                                                  float* __restrict__ maxPart, int m0) {
  int mL = blockIdx.x >> 4;
  int seg = blockIdx.x & 15;
  const float4* p = (const float4*)(Dreg + (size_t)mL * NN2 + (size_t)seg * 16384);
  float mx = 0.f;
  for (int i = threadIdx.x; i < 4096; i += 256) {
    float4 v = p[i];
    mx = fmaxf(mx, fmaxf(fmaxf(v.x, v.y), fmaxf(v.z, v.w)));
  }
  #pragma unroll
  for (int off = 32; off > 0; off >>= 1) mx = fmaxf(mx, __shfl_down(mx, off));
  __shared__ float red[4];
  if ((threadIdx.x & 63) == 0) red[threadIdx.x >> 6] = mx;
  __syncthreads();
  if (threadIdx.x == 0) {
    float r = fmaxf(fmaxf(red[0], red[1]), fmaxf(red[2], red[3]));
    maxPart[(size_t)(m0 + mL) * 16 + seg] = r;
  }
}

__global__ void max_fin(const float* __restrict__ maxPart, float* __restrict__ maxD,
                        int m0, int nm) {
  int t = threadIdx.x;
  if (t < nm) {
    int m = m0 + t;
    float mx = 0.f;
    #pragma unroll
    for (int i = 0; i < 16; ++i) mx = fmaxf(mx, maxPart[(size_t)m * 16 + i]);
    maxD[m] = fmaxf(mx, 1e-12f);
  }
}

// ---------------- Prim MST: 1 wave per matrix, md in regs, mf in LDS ------------
__global__ __launch_bounds__(64) void mst_kernel(const float* __restrict__ Dreg,
                                                 int2* __restrict__ edges, int m0) {
  int mL = blockIdx.x;
  int m = m0 + mL;
  const float* D = Dreg + (size_t)mL * NN2;
  __shared__ int mf[NN];
  int lane = threadIdx.x;
  int base = lane * 8;
  float md[8];
  float4 r0 = *(const float4*)(D + base);
  float4 r1 = *(const float4*)(D + base + 4);
  md[0] = r0.x; md[1] = r0.y; md[2] = r0.z; md[3] = r0.w;
  md[4] = r1.x; md[5] = r1.y; md[6] = r1.z; md[7] = r1.w;
  if (lane == 0) md[0] = FLTMAX;          // node 0 in tree
  #pragma unroll
  for (int k = 0; k < 8; ++k) mf[base + k] = 0;
  int2* eo = edges + (size_t)m * (NN - 1);

  for (int s = 0; s < NN - 1; ++s) {
    // local argmin over my 8 (strict < keeps smallest index)
    float bv = md[0]; int bc = base;
    #pragma unroll
    for (int k = 1; k < 8; ++k) { if (md[k] < bv) { bv = md[k]; bc = base + k; } }
    // wave argmin, lexicographic (value, index) => first-index tie-break like jnp.argmin
    #pragma unroll
    for (int off = 1; off < 64; off <<= 1) {
      float ov = __shfl_xor(bv, off);
      int   oc = __shfl_xor(bc, off);
      if (ov < bv || (ov == bv && oc < bc)) { bv = ov; bc = oc; }
    }
    int j = bc;
    int i = mf[j];                         // LDS broadcast (same-wave DS ops are in-order)
    if (lane == 0) eo[s] = make_int2(i, j);
    #pragma unroll
    for (int k = 0; k < 8; ++k) if (base + k == j) md[k] = FLTMAX;   // insert j
    const float* rj = D + (size_t)j * NN + base;
    float4 v0 = *(const float4*)rj;
    float4 v1 = *(const float4*)(rj + 4);
    float dv[8] = {v0.x, v0.y, v0.z, v0.w, v1.x, v1.y, v1.z, v1.w};
    #pragma unroll
    for (int k = 0; k < 8; ++k) {
      if (md[k] != FLTMAX && dv[k] < md[k]) { md[k] = dv[k]; mf[base + k] = j; }
    }
  }
}

// ---------------- gather loss over MST edges ------------------------------------
__global__ __launch_bounds__(256) void gather_kernel(const float* __restrict__ Dreg,
                                                     const float* __restrict__ maxD,
                                                     const int2* __restrict__ edges,
                                                     float* __restrict__ out,
                                                     int m0, int nm) {
  int total = nm * (NN - 1);
  float acc = 0.f;
  for (int it = threadIdx.x; it < total; it += 256) {
    int lm = it / (NN - 1);
    int s = it - lm * (NN - 1);
    int m = m0 + lm;
    int b = m >> 1;
    int lb = b - (m0 >> 1);
    int2 e = edges[(size_t)m * (NN - 1) + s];
    const float* Dx = Dreg + (size_t)(2 * lb) * NN2;
    const float* Dz = Dreg + (size_t)(2 * lb + 1) * NN2;
    size_t off = (size_t)e.x * NN + e.y;
    float d = Dx[off] / maxD[2 * b] - Dz[off] / maxD[2 * b + 1];
    acc += d * d;
  }
  __shared__ float red[256];
  red[threadIdx.x] = acc;
  __syncthreads();
  for (int h = 128; h > 0; h >>= 1) {
    if (threadIdx.x < h) red[threadIdx.x] += red[threadIdx.x + h];
    __syncthreads();
  }
  if (threadIdx.x == 0) atomicAdd(out, red[0] * (1.0f / NB));
}

extern "C" void kernel_launch(void* const* d_in, const int* in_sizes, int n_in,
                              void* d_out, int out_size, void* d_ws, size_t ws_size,
                              hipStream_t stream) {
  const float* model = (const float*)d_in[0];
  const float* labels = (const float*)d_in[1];
  float* out = (float*)d_out;
  char* ws = (char*)d_ws;

  // workspace layout
  float* sq      = (float*)(ws);            // 64*512 f32  = 131072 B
  float* maxD    = (float*)(ws + 131072);   // 64 f32 (padded to 1024)
  float* maxPart = (float*)(ws + 132096);   // 64*16 f32   = 4096 B
  int2*  edges   = (int2*)(ws + 136192);    // 64*511 int2 = 261632 B
  float* Dreg    = (float*)(ws + 524288);   // chunked D matrices, 1 MB each

  size_t dcap = (ws_size > 524288) ? (ws_size - 524288) : 0;
  int cb = (int)(dcap / (2ull * sizeof(float) * NN2));   // batches per chunk
  if (cb > NB) cb = NB;
  if (cb < 1) cb = 1;

  hipMemsetAsync(d_out, 0, sizeof(float), stream);
  sq_kernel<<<8192, 256, 0, stream>>>(model, labels, sq);

  for (int b0 = 0; b0 < NB; b0 += cb) {
    int nb = (NB - b0 < cb) ? (NB - b0) : cb;
    int nm = 2 * nb, m0 = 2 * b0;
    gemm_dist<<<dim3(8, 8, nm), 256, 0, stream>>>(model, labels, sq, Dreg, m0);
    max_kernel<<<nm * 16, 256, 0, stream>>>(Dreg, maxPart, m0);
    max_fin<<<1, 64, 0, stream>>>(maxPart, maxD, m0, nm);
    mst_kernel<<<nm, 64, 0, stream>>>(Dreg, edges, m0);
    gather_kernel<<<1, 256, 0, stream>>>(Dreg, maxD, edges, out, m0, nm);
  }
}

// Round 2
// 690.510 us; speedup vs baseline: 1.4236x; 1.4236x over previous
//
#include <hip/hip_runtime.h>
#include <math.h>

#define NN 512
#define NN2 (NN*NN)
#define NB 32
#define NM 64
#define FLTMAX 3.402823466e38f

__device__ __forceinline__ float sigm(float x) { return 1.0f / (1.0f + expf(-x)); }

__device__ __forceinline__ unsigned long long u64min(unsigned long long a,
                                                     unsigned long long b) {
  return (b < a) ? b : a;
}

// ---------------- row sums of squares (with sigmoid for X matrices) -------------
__global__ __launch_bounds__(256) void sq_kernel(const float* __restrict__ model,
                                                 const float* __restrict__ labels,
                                                 float* __restrict__ sq) {
  int gw = blockIdx.x * 4 + (threadIdx.x >> 6);   // global wave id = matrix*512 + row
  int lane = threadIdx.x & 63;
  int m = gw >> 9;
  int row = gw & 511;
  if (m >= NM) return;
  const float* src = (m & 1) ? labels + (size_t)(m >> 1) * NN2
                             : model + (size_t)(m >> 1) * NN2;
  bool sg = !(m & 1);
  const float4* rp = (const float4*)(src + (size_t)row * NN);
  float s = 0.f;
  #pragma unroll
  for (int c = 0; c < 2; ++c) {
    float4 v = rp[lane + c * 64];
    if (sg) { v.x = sigm(v.x); v.y = sigm(v.y); v.z = sigm(v.z); v.w = sigm(v.w); }
    s += v.x * v.x + v.y * v.y + v.z * v.z + v.w * v.w;
  }
  #pragma unroll
  for (int off = 32; off > 0; off >>= 1) s += __shfl_down(s, off);
  if (lane == 0) sq[(size_t)m * NN + row] = s;
}

// ------- distance matrix via fp32 tiled GEMM (G = X X^T) + fused max ------------
__global__ __launch_bounds__(256) void gemm_dist(const float* __restrict__ model,
                                                 const float* __restrict__ labels,
                                                 const float* __restrict__ sq,
                                                 float* __restrict__ Dreg,
                                                 unsigned* __restrict__ maxBits, int m0) {
  __shared__ float As[32][68];
  __shared__ float Bs[32][68];
  int mL = blockIdx.z;
  int m = m0 + mL;
  const float* src = (m & 1) ? labels + (size_t)(m >> 1) * NN2
                             : model + (size_t)(m >> 1) * NN2;
  bool sg = !(m & 1);
  int by = blockIdx.y, bx = blockIdx.x;
  int tid = threadIdx.x;
  int lr = tid >> 2;             // 0..63: row within tile panel
  int kq = (tid & 3) * 8;        // 0,8,16,24: k-offset of this thread's 8 elements
  int ty = tid >> 4, tx = tid & 15;
  float acc[4][4] = {};
  const float* arow = src + (size_t)(by * 64 + lr) * NN + kq;
  const float* brow = src + (size_t)(bx * 64 + lr) * NN + kq;

  for (int k0 = 0; k0 < NN; k0 += 32) {
    float4 a0 = *(const float4*)(arow + k0);
    float4 a1 = *(const float4*)(arow + k0 + 4);
    float4 b0 = *(const float4*)(brow + k0);
    float4 b1 = *(const float4*)(brow + k0 + 4);
    if (sg) {
      a0.x = sigm(a0.x); a0.y = sigm(a0.y); a0.z = sigm(a0.z); a0.w = sigm(a0.w);
      a1.x = sigm(a1.x); a1.y = sigm(a1.y); a1.z = sigm(a1.z); a1.w = sigm(a1.w);
      b0.x = sigm(b0.x); b0.y = sigm(b0.y); b0.z = sigm(b0.z); b0.w = sigm(b0.w);
      b1.x = sigm(b1.x); b1.y = sigm(b1.y); b1.z = sigm(b1.z); b1.w = sigm(b1.w);
    }
    As[kq + 0][lr] = a0.x; As[kq + 1][lr] = a0.y; As[kq + 2][lr] = a0.z; As[kq + 3][lr] = a0.w;
    As[kq + 4][lr] = a1.x; As[kq + 5][lr] = a1.y; As[kq + 6][lr] = a1.z; As[kq + 7][lr] = a1.w;
    Bs[kq + 0][lr] = b0.x; Bs[kq + 1][lr] = b0.y; Bs[kq + 2][lr] = b0.z; Bs[kq + 3][lr] = b0.w;
    Bs[kq + 4][lr] = b1.x; Bs[kq + 5][lr] = b1.y; Bs[kq + 6][lr] = b1.z; Bs[kq + 7][lr] = b1.w;
    __syncthreads();
    #pragma unroll
    for (int kk = 0; kk < 32; ++kk) {
      const float4 a4 = *(const float4*)&As[kk][ty * 4];
      const float4 b4 = *(const float4*)&Bs[kk][tx * 4];
      const float av[4] = {a4.x, a4.y, a4.z, a4.w};
      const float bv[4] = {b4.x, b4.y, b4.z, b4.w};
      #pragma unroll
      for (int r = 0; r < 4; ++r)
        #pragma unroll
        for (int c = 0; c < 4; ++c)
          acc[r][c] = fmaf(av[r], bv[c], acc[r][c]);
    }
    __syncthreads();
  }

  const float* sqm = sq + (size_t)m * NN;
  float sqi[4], sqj[4];
  #pragma unroll
  for (int r = 0; r < 4; ++r) sqi[r] = sqm[by * 64 + ty * 4 + r];
  #pragma unroll
  for (int c = 0; c < 4; ++c) sqj[c] = sqm[bx * 64 + tx * 4 + c];
  float* drow = Dreg + (size_t)mL * NN2 + (size_t)(by * 64 + ty * 4) * NN + bx * 64 + tx * 4;
  float tmax = 0.f;
  #pragma unroll
  for (int r = 0; r < 4; ++r) {
    float4 o;
    o.x = sqrtf(fmaxf(sqi[r] + sqj[0] - 2.f * acc[r][0], 0.f));
    o.y = sqrtf(fmaxf(sqi[r] + sqj[1] - 2.f * acc[r][1], 0.f));
    o.z = sqrtf(fmaxf(sqi[r] + sqj[2] - 2.f * acc[r][2], 0.f));
    o.w = sqrtf(fmaxf(sqi[r] + sqj[3] - 2.f * acc[r][3], 0.f));
    *(float4*)(drow + (size_t)r * NN) = o;
    tmax = fmaxf(tmax, fmaxf(fmaxf(o.x, o.y), fmaxf(o.z, o.w)));
  }
  // fused per-matrix max: wave reduce, then one atomic per wave
  #pragma unroll
  for (int off = 32; off > 0; off >>= 1) tmax = fmaxf(tmax, __shfl_down(tmax, off));
  if ((tid & 63) == 0) atomicMax(&maxBits[m], __float_as_uint(tmax));
}

// ---------------- Prim MST: 1 wave per matrix, md+mf fully in registers ---------
__global__ __launch_bounds__(64) void mst_kernel(const float* __restrict__ Dreg,
                                                 int2* __restrict__ edges, int m0) {
  int mL = blockIdx.x;
  int m = m0 + mL;
  const float* D = Dreg + (size_t)mL * NN2;
  int lane = threadIdx.x;
  int base = lane * 8;
  float md[8];
  int   mf[8];
  float4 r0 = *(const float4*)(D + base);
  float4 r1 = *(const float4*)(D + base + 4);
  md[0] = r0.x; md[1] = r0.y; md[2] = r0.z; md[3] = r0.w;
  md[4] = r1.x; md[5] = r1.y; md[6] = r1.z; md[7] = r1.w;
  if (lane == 0) md[0] = FLTMAX;          // node 0 in tree
  #pragma unroll
  for (int k = 0; k < 8; ++k) mf[k] = 0;
  int2* eo = edges + (size_t)m * (NN - 1);

  for (int s = 0; s < NN - 1; ++s) {
    // ---- local argmin over my 8 nodes: packed (valueBits<<32 | index) u64 tree.
    // fp32 >= 0 so bit pattern is order-monotone; min key = (min value, min index)
    // => first-index tie-break, matching jnp.argmin.
    unsigned long long k0, k1, k2, k3, k4, k5, k6, k7;
    k0 = ((unsigned long long)__float_as_uint(md[0]) << 32) | (unsigned)(base + 0);
    k1 = ((unsigned long long)__float_as_uint(md[1]) << 32) | (unsigned)(base + 1);
    k2 = ((unsigned long long)__float_as_uint(md[2]) << 32) | (unsigned)(base + 2);
    k3 = ((unsigned long long)__float_as_uint(md[3]) << 32) | (unsigned)(base + 3);
    k4 = ((unsigned long long)__float_as_uint(md[4]) << 32) | (unsigned)(base + 4);
    k5 = ((unsigned long long)__float_as_uint(md[5]) << 32) | (unsigned)(base + 5);
    k6 = ((unsigned long long)__float_as_uint(md[6]) << 32) | (unsigned)(base + 6);
    k7 = ((unsigned long long)__float_as_uint(md[7]) << 32) | (unsigned)(base + 7);
    unsigned long long key = u64min(u64min(u64min(k0, k1), u64min(k2, k3)),
                                    u64min(u64min(k4, k5), u64min(k6, k7)));
    // ---- wave argmin: 6-step butterfly on the packed key
    #pragma unroll
    for (int off = 1; off < 64; off <<= 1) {
      unsigned long long o = __shfl_xor(key, off);
      key = u64min(key, o);
    }
    int j = (int)(unsigned)key;

    // ---- issue row load ASAP (critical path: j -> load -> update)
    const float* rj = D + (size_t)j * NN + base;
    float4 v0 = *(const float4*)rj;
    float4 v1 = *(const float4*)(rj + 4);

    // ---- bookkeeping in the load shadow: edge store by the owning lane
    if ((j >> 3) == lane) {
      int iv = mf[0];
      #pragma unroll
      for (int k = 1; k < 8; ++k) iv = ((j & 7) == k) ? mf[k] : iv;
      eo[s] = make_int2(iv, j);
      #pragma unroll
      for (int k = 0; k < 8; ++k) if ((j & 7) == k) md[k] = FLTMAX;   // insert j
    }

    float dv[8] = {v0.x, v0.y, v0.z, v0.w, v1.x, v1.y, v1.z, v1.w};
    #pragma unroll
    for (int k = 0; k < 8; ++k) {
      if (md[k] != FLTMAX && dv[k] < md[k]) { md[k] = dv[k]; mf[k] = j; }
    }
  }
}

// ---------------- gather loss over MST edges (one block per matrix) -------------
__global__ __launch_bounds__(256) void gather_kernel(const float* __restrict__ Dreg,
                                                     const unsigned* __restrict__ maxBits,
                                                     const int2* __restrict__ edges,
                                                     float* __restrict__ out,
                                                     int m0) {
  int lm = blockIdx.x;
  int m = m0 + lm;
  int b = m >> 1;
  int lb = lm >> 1;
  float mxX = fmaxf(__uint_as_float(maxBits[2 * b]), 1e-12f);
  float mxZ = fmaxf(__uint_as_float(maxBits[2 * b + 1]), 1e-12f);
  float rX = 1.0f / mxX, rZ = 1.0f / mxZ;
  const float* Dx = Dreg + (size_t)(2 * lb) * NN2;
  const float* Dz = Dreg + (size_t)(2 * lb + 1) * NN2;
  const int2* eo = edges + (size_t)m * (NN - 1);
  float acc = 0.f;
  for (int s = threadIdx.x; s < NN - 1; s += 256) {
    int2 e = eo[s];
    size_t off = (size_t)e.x * NN + e.y;
    float d = Dx[off] * rX - Dz[off] * rZ;
    acc += d * d;
  }
  __shared__ float red[256];
  red[threadIdx.x] = acc;
  __syncthreads();
  for (int h = 128; h > 0; h >>= 1) {
    if (threadIdx.x < h) red[threadIdx.x] += red[threadIdx.x + h];
    __syncthreads();
  }
  if (threadIdx.x == 0) atomicAdd(out, red[0] * (1.0f / NB));
}

extern "C" void kernel_launch(void* const* d_in, const int* in_sizes, int n_in,
                              void* d_out, int out_size, void* d_ws, size_t ws_size,
                              hipStream_t stream) {
  const float* model = (const float*)d_in[0];
  const float* labels = (const float*)d_in[1];
  float* out = (float*)d_out;
  char* ws = (char*)d_ws;

  // workspace layout
  float*    sq      = (float*)(ws);            // 64*512 f32  = 131072 B
  unsigned* maxBits = (unsigned*)(ws + 131072);// 64 u32 = 256 B (pad to 1024)
  int2*     edges   = (int2*)(ws + 132096);    // 64*511 int2 = 261632 B
  float*    Dreg    = (float*)(ws + 524288);   // chunked D matrices, 1 MB each

  size_t dcap = (ws_size > 524288) ? (ws_size - 524288) : 0;
  int cb = (int)(dcap / (2ull * sizeof(float) * NN2));   // batches per chunk
  if (cb > NB) cb = NB;
  if (cb < 1) cb = 1;

  hipMemsetAsync(d_out, 0, sizeof(float), stream);
  hipMemsetAsync(maxBits, 0, 64 * sizeof(unsigned), stream);
  sq_kernel<<<8192, 256, 0, stream>>>(model, labels, sq);

  for (int b0 = 0; b0 < NB; b0 += cb) {
    int nb = (NB - b0 < cb) ? (NB - b0) : cb;
    int nm = 2 * nb, m0 = 2 * b0;
    gemm_dist<<<dim3(8, 8, nm), 256, 0, stream>>>(model, labels, sq, Dreg, maxBits, m0);
    mst_kernel<<<nm, 64, 0, stream>>>(Dreg, edges, m0);
    gather_kernel<<<nm, 256, 0, stream>>>(Dreg, maxBits, edges, out, m0);
  }
}

// Round 3
// 573.097 us; speedup vs baseline: 1.7152x; 1.2049x over previous
//
#include <hip/hip_runtime.h>
#include <math.h>

#define NN 512
#define NN2 (NN*NN)
#define NB 32
#define NM 64
#define FLTMAX 3.402823466e38f
#define LST 140                       // LDS row stride (floats), skewed layout
#define LADDR(k, r) ((k)*LST + (r) + ((((r) >> 5)) << 2))

__device__ __forceinline__ float sigm(float x) { return 1.0f / (1.0f + expf(-x)); }

template <int CTRL>
__device__ __forceinline__ float dpp_min_f32(float x) {
  int y = __builtin_amdgcn_update_dpp(__float_as_int(x), __float_as_int(x), CTRL, 0xf, 0xf, false);
  return fminf(x, __int_as_float(y));
}
template <int CTRL>
__device__ __forceinline__ unsigned dpp_min_u32(unsigned x) {
  unsigned y = (unsigned)__builtin_amdgcn_update_dpp((int)x, (int)x, CTRL, 0xf, 0xf, false);
  return (y < x) ? y : x;
}

// ---------------- row sums of squares (with sigmoid for X matrices) -------------
__global__ __launch_bounds__(256) void sq_kernel(const float* __restrict__ model,
                                                 const float* __restrict__ labels,
                                                 float* __restrict__ sq) {
  int gw = blockIdx.x * 4 + (threadIdx.x >> 6);
  int lane = threadIdx.x & 63;
  int m = gw >> 9;
  int row = gw & 511;
  if (m >= NM) return;
  const float* src = (m & 1) ? labels + (size_t)(m >> 1) * NN2
                             : model + (size_t)(m >> 1) * NN2;
  bool sg = !(m & 1);
  const float4* rp = (const float4*)(src + (size_t)row * NN);
  float s = 0.f;
  #pragma unroll
  for (int c = 0; c < 2; ++c) {
    float4 v = rp[lane + c * 64];
    if (sg) { v.x = sigm(v.x); v.y = sigm(v.y); v.z = sigm(v.z); v.w = sigm(v.w); }
    s += v.x * v.x + v.y * v.y + v.z * v.z + v.w * v.w;
  }
  #pragma unroll
  for (int off = 32; off > 0; off >>= 1) s += __shfl_down(s, off);
  if (lane == 0) sq[(size_t)m * NN + row] = s;
}

// ------- distance matrix: 128x128 tiles, 8x8 micro, upper triangle + mirror -----
__global__ __launch_bounds__(256) void gemm_dist(const float* __restrict__ model,
                                                 const float* __restrict__ labels,
                                                 const float* __restrict__ sq,
                                                 float* __restrict__ Dreg,
                                                 unsigned* __restrict__ maxBits, int m0) {
  __shared__ float As[32 * LST + 16];
  __shared__ float Bs[32 * LST + 16];
  int p = blockIdx.x;                 // 0..9: upper-triangle pair index of 4x4 tiles
  int by = (p >= 4) + (p >= 7) + (p >= 9);
  int bx = p - ((by * (7 - by)) >> 1);
  int mL = blockIdx.y;
  int m = m0 + mL;
  const float* src = (m & 1) ? labels + (size_t)(m >> 1) * NN2
                             : model + (size_t)(m >> 1) * NN2;
  bool sg = !(m & 1);
  int tid = threadIdx.x;
  int ty = tid >> 4, tx = tid & 15;   // 16x16 thread grid, 8x8 micro-tile
  int sr = tid >> 3;                  // staging row 0..31
  int sc = (tid & 7) * 4;             // staging k-offset 0..28

  const float* aptr = src + (size_t)(by * 128 + sr) * NN + sc;
  const float* bptr = src + (size_t)(bx * 128 + sr) * NN + sc;
  int aoff = ty * 8 + ((ty >> 2) << 2);   // skewed read col for A rows
  int boff = tx * 8 + ((tx >> 2) << 2);   // skewed read col for B cols

  float acc[8][8] = {};

  for (int k0 = 0; k0 < NN; k0 += 32) {
    float4 av[4], bv[4];
    #pragma unroll
    for (int i = 0; i < 4; ++i) {
      av[i] = *(const float4*)(aptr + (size_t)(i * 32) * NN + k0);
      bv[i] = *(const float4*)(bptr + (size_t)(i * 32) * NN + k0);
    }
    if (sg) {
      #pragma unroll
      for (int i = 0; i < 4; ++i) {
        av[i].x = sigm(av[i].x); av[i].y = sigm(av[i].y); av[i].z = sigm(av[i].z); av[i].w = sigm(av[i].w);
        bv[i].x = sigm(bv[i].x); bv[i].y = sigm(bv[i].y); bv[i].z = sigm(bv[i].z); bv[i].w = sigm(bv[i].w);
      }
    }
    __syncthreads();                  // previous iteration's reads done
    #pragma unroll
    for (int i = 0; i < 4; ++i) {
      int r = sr + i * 32;
      As[LADDR(sc + 0, r)] = av[i].x; As[LADDR(sc + 1, r)] = av[i].y;
      As[LADDR(sc + 2, r)] = av[i].z; As[LADDR(sc + 3, r)] = av[i].w;
      Bs[LADDR(sc + 0, r)] = bv[i].x; Bs[LADDR(sc + 1, r)] = bv[i].y;
      Bs[LADDR(sc + 2, r)] = bv[i].z; Bs[LADDR(sc + 3, r)] = bv[i].w;
    }
    __syncthreads();
    #pragma unroll
    for (int kk = 0; kk < 32; ++kk) {
      float4 a0 = *(const float4*)&As[kk * LST + aoff];
      float4 a1 = *(const float4*)&As[kk * LST + aoff + 4];
      float4 b0 = *(const float4*)&Bs[kk * LST + boff];
      float4 b1 = *(const float4*)&Bs[kk * LST + boff + 4];
      float a[8] = {a0.x, a0.y, a0.z, a0.w, a1.x, a1.y, a1.z, a1.w};
      float b[8] = {b0.x, b0.y, b0.z, b0.w, b1.x, b1.y, b1.z, b1.w};
      #pragma unroll
      for (int r = 0; r < 8; ++r)
        #pragma unroll
        for (int c = 0; c < 8; ++c)
          acc[r][c] = fmaf(a[r], b[c], acc[r][c]);
    }
  }

  const float* sqm = sq + (size_t)m * NN;
  float sqi[8], sqj[8];
  #pragma unroll
  for (int r = 0; r < 8; ++r) sqi[r] = sqm[by * 128 + ty * 8 + r];
  #pragma unroll
  for (int c = 0; c < 8; ++c) sqj[c] = sqm[bx * 128 + tx * 8 + c];

  float tmax = 0.f;
  #pragma unroll
  for (int r = 0; r < 8; ++r) {
    #pragma unroll
    for (int c = 0; c < 8; ++c) {
      float v = sqrtf(fmaxf(sqi[r] + sqj[c] - 2.f * acc[r][c], 0.f));
      acc[r][c] = v;
      tmax = fmaxf(tmax, v);
    }
  }

  float* Dm = Dreg + (size_t)mL * NN2;
  int gr0 = by * 128 + ty * 8, gc0 = bx * 128 + tx * 8;
  #pragma unroll
  for (int r = 0; r < 8; ++r) {
    float4 o0 = make_float4(acc[r][0], acc[r][1], acc[r][2], acc[r][3]);
    float4 o1 = make_float4(acc[r][4], acc[r][5], acc[r][6], acc[r][7]);
    *(float4*)(Dm + (size_t)(gr0 + r) * NN + gc0) = o0;
    *(float4*)(Dm + (size_t)(gr0 + r) * NN + gc0 + 4) = o1;
  }
  if (by != bx) {
    #pragma unroll
    for (int c = 0; c < 8; ++c) {
      float4 o0 = make_float4(acc[0][c], acc[1][c], acc[2][c], acc[3][c]);
      float4 o1 = make_float4(acc[4][c], acc[5][c], acc[6][c], acc[7][c]);
      *(float4*)(Dm + (size_t)(gc0 + c) * NN + gr0) = o0;
      *(float4*)(Dm + (size_t)(gc0 + c) * NN + gr0 + 4) = o1;
    }
  }
  #pragma unroll
  for (int off = 32; off > 0; off >>= 1) tmax = fmaxf(tmax, __shfl_down(tmax, off));
  if ((tid & 63) == 0) atomicMax(&maxBits[m], __float_as_uint(tmax));
}

// ---------------- Prim MST: 1 wave per matrix, DPP argmin reductions ------------
__global__ __launch_bounds__(64) void mst_kernel(const float* __restrict__ Dreg,
                                                 int2* __restrict__ edges, int m0) {
  int mL = blockIdx.x;
  int m = m0 + mL;
  const float* D = Dreg + (size_t)mL * NN2;
  int lane = threadIdx.x;
  int base = lane * 8;
  float md[8];
  int   mf[8];
  float4 r0 = *(const float4*)(D + base);
  float4 r1 = *(const float4*)(D + base + 4);
  md[0] = r0.x; md[1] = r0.y; md[2] = r0.z; md[3] = r0.w;
  md[4] = r1.x; md[5] = r1.y; md[6] = r1.z; md[7] = r1.w;
  if (lane == 0) md[0] = FLTMAX;          // node 0 in tree
  #pragma unroll
  for (int k = 0; k < 8; ++k) mf[k] = 0;
  int2* eo = edges + (size_t)m * (NN - 1);

  for (int s = 0; s < NN - 1; ++s) {
    // local 8-way min value (tree)
    float v = fminf(fminf(fminf(md[0], md[1]), fminf(md[2], md[3])),
                    fminf(fminf(md[4], md[5]), fminf(md[6], md[7])));
    // wave min via DPP (row_shr 1,2,4,8 then bcast15, bcast31; result in lane 63)
    v = dpp_min_f32<0x111>(v);
    v = dpp_min_f32<0x112>(v);
    v = dpp_min_f32<0x114>(v);
    v = dpp_min_f32<0x118>(v);
    v = dpp_min_f32<0x142>(v);
    v = dpp_min_f32<0x143>(v);
    float vmin = __int_as_float(__builtin_amdgcn_readlane(__float_as_int(v), 63));
    // first matching index (ties -> smallest index, = jnp.argmin)
    unsigned cand = 0xffffffffu;
    #pragma unroll
    for (int k = 7; k >= 0; --k) if (md[k] == vmin) cand = (unsigned)(base + k);
    cand = dpp_min_u32<0x111>(cand);
    cand = dpp_min_u32<0x112>(cand);
    cand = dpp_min_u32<0x114>(cand);
    cand = dpp_min_u32<0x118>(cand);
    cand = dpp_min_u32<0x142>(cand);
    cand = dpp_min_u32<0x143>(cand);
    int j = __builtin_amdgcn_readlane((int)cand, 63);

    // issue row load ASAP (chain: j -> load -> update)
    const float* rj = D + (size_t)j * NN + base;
    float4 v0 = *(const float4*)rj;
    float4 v1 = *(const float4*)(rj + 4);

    // bookkeeping in the load shadow: owning lane emits the edge, inserts j
    if ((j >> 3) == lane) {
      int iv = mf[0];
      #pragma unroll
      for (int k = 1; k < 8; ++k) iv = ((j & 7) == k) ? mf[k] : iv;
      eo[s] = make_int2(iv, j);
      #pragma unroll
      for (int k = 0; k < 8; ++k) if ((j & 7) == k) md[k] = FLTMAX;
    }

    float dv[8] = {v0.x, v0.y, v0.z, v0.w, v1.x, v1.y, v1.z, v1.w};
    #pragma unroll
    for (int k = 0; k < 8; ++k) {
      if (md[k] != FLTMAX && dv[k] < md[k]) { md[k] = dv[k]; mf[k] = j; }
    }
  }
}

// ---------------- gather loss over MST edges (one block per matrix) -------------
__global__ __launch_bounds__(256) void gather_kernel(const float* __restrict__ Dreg,
                                                     const unsigned* __restrict__ maxBits,
                                                     const int2* __restrict__ edges,
                                                     float* __restrict__ out,
                                                     int m0) {
  int lm = blockIdx.x;
  int m = m0 + lm;
  int b = m >> 1;
  int lb = lm >> 1;
  float mxX = fmaxf(__uint_as_float(maxBits[2 * b]), 1e-12f);
  float mxZ = fmaxf(__uint_as_float(maxBits[2 * b + 1]), 1e-12f);
  float rX = 1.0f / mxX, rZ = 1.0f / mxZ;
  const float* Dx = Dreg + (size_t)(2 * lb) * NN2;
  const float* Dz = Dreg + (size_t)(2 * lb + 1) * NN2;
  const int2* eo = edges + (size_t)m * (NN - 1);
  float acc = 0.f;
  for (int s = threadIdx.x; s < NN - 1; s += 256) {
    int2 e = eo[s];
    size_t off = (size_t)e.x * NN + e.y;
    float d = Dx[off] * rX - Dz[off] * rZ;
    acc += d * d;
  }
  __shared__ float red[256];
  red[threadIdx.x] = acc;
  __syncthreads();
  for (int h = 128; h > 0; h >>= 1) {
    if (threadIdx.x < h) red[threadIdx.x] += red[threadIdx.x + h];
    __syncthreads();
  }
  if (threadIdx.x == 0) atomicAdd(out, red[0] * (1.0f / NB));
}

extern "C" void kernel_launch(void* const* d_in, const int* in_sizes, int n_in,
                              void* d_out, int out_size, void* d_ws, size_t ws_size,
                              hipStream_t stream) {
  const float* model = (const float*)d_in[0];
  const float* labels = (const float*)d_in[1];
  float* out = (float*)d_out;
  char* ws = (char*)d_ws;

  float*    sq      = (float*)(ws);             // 64*512 f32  = 131072 B
  unsigned* maxBits = (unsigned*)(ws + 131072); // 64 u32
  int2*     edges   = (int2*)(ws + 132096);     // 64*511 int2 = 261632 B
  float*    Dreg    = (float*)(ws + 524288);    // chunked D matrices, 1 MB each

  size_t dcap = (ws_size > 524288) ? (ws_size - 524288) : 0;
  int cb = (int)(dcap / (2ull * sizeof(float) * NN2));
  if (cb > NB) cb = NB;
  if (cb < 1) cb = 1;

  hipMemsetAsync(d_out, 0, sizeof(float), stream);
  hipMemsetAsync(maxBits, 0, 64 * sizeof(unsigned), stream);
  sq_kernel<<<8192, 256, 0, stream>>>(model, labels, sq);

  for (int b0 = 0; b0 < NB; b0 += cb) {
    int nb = (NB - b0 < cb) ? (NB - b0) : cb;
    int nm = 2 * nb, m0 = 2 * b0;
    gemm_dist<<<dim3(10, nm), 256, 0, stream>>>(model, labels, sq, Dreg, maxBits, m0);
    mst_kernel<<<nm, 64, 0, stream>>>(Dreg, edges, m0);
    gather_kernel<<<nm, 256, 0, stream>>>(Dreg, maxBits, edges, out, m0);
  }
}

// Round 4
// 537.599 us; speedup vs baseline: 1.8285x; 1.0660x over previous
//
#include <hip/hip_runtime.h>
#include <math.h>

#define NN 512
#define NN2 (NN*NN)
#define NB 32
#define NM 64
#define FLTMAX 3.402823466e38f
#define LST 140                       // LDS row stride (floats), skewed layout
#define LADDR(k, r) ((k)*LST + (r) + ((((r) >> 5)) << 2))

__device__ __forceinline__ float sigm(float x) { return 1.0f / (1.0f + expf(-x)); }

// portable u64 atomic-min on LDS via CAS loop (low contention here)
__device__ __forceinline__ void amin64(unsigned long long* p, unsigned long long v) {
  unsigned long long old = *p;
  while (v < old) {
    unsigned long long assumed = old;
    old = atomicCAS(p, assumed, v);
    if (old == assumed) break;
  }
}

// ---------------- row sums of squares (with sigmoid for X matrices) -------------
__global__ __launch_bounds__(256) void sq_kernel(const float* __restrict__ model,
                                                 const float* __restrict__ labels,
                                                 float* __restrict__ sq) {
  int gw = blockIdx.x * 4 + (threadIdx.x >> 6);
  int lane = threadIdx.x & 63;
  int m = gw >> 9;
  int row = gw & 511;
  if (m >= NM) return;
  const float* src = (m & 1) ? labels + (size_t)(m >> 1) * NN2
                             : model + (size_t)(m >> 1) * NN2;
  bool sg = !(m & 1);
  const float4* rp = (const float4*)(src + (size_t)row * NN);
  float s = 0.f;
  #pragma unroll
  for (int c = 0; c < 2; ++c) {
    float4 v = rp[lane + c * 64];
    if (sg) { v.x = sigm(v.x); v.y = sigm(v.y); v.z = sigm(v.z); v.w = sigm(v.w); }
    s += v.x * v.x + v.y * v.y + v.z * v.z + v.w * v.w;
  }
  #pragma unroll
  for (int off = 32; off > 0; off >>= 1) s += __shfl_down(s, off);
  if (lane == 0) sq[(size_t)m * NN + row] = s;
}

// ------- distance matrix: 128x128 tiles, 8x8 micro, upper triangle + mirror -----
__global__ __launch_bounds__(256) void gemm_dist(const float* __restrict__ model,
                                                 const float* __restrict__ labels,
                                                 const float* __restrict__ sq,
                                                 float* __restrict__ Dreg,
                                                 unsigned* __restrict__ maxBits, int m0) {
  __shared__ float As[32 * LST + 16];
  __shared__ float Bs[32 * LST + 16];
  int p = blockIdx.x;                 // 0..9: upper-triangle pair index of 4x4 tiles
  int by = (p >= 4) + (p >= 7) + (p >= 9);
  int bx = p - ((by * (7 - by)) >> 1);
  int mL = blockIdx.y;
  int m = m0 + mL;
  const float* src = (m & 1) ? labels + (size_t)(m >> 1) * NN2
                             : model + (size_t)(m >> 1) * NN2;
  bool sg = !(m & 1);
  int tid = threadIdx.x;
  int ty = tid >> 4, tx = tid & 15;   // 16x16 thread grid, 8x8 micro-tile
  int sr = tid >> 3;                  // staging row 0..31
  int sc = (tid & 7) * 4;             // staging k-offset 0..28

  const float* aptr = src + (size_t)(by * 128 + sr) * NN + sc;
  const float* bptr = src + (size_t)(bx * 128 + sr) * NN + sc;
  int aoff = ty * 8 + ((ty >> 2) << 2);   // skewed read col for A rows
  int boff = tx * 8 + ((tx >> 2) << 2);   // skewed read col for B cols

  float acc[8][8] = {};

  for (int k0 = 0; k0 < NN; k0 += 32) {
    float4 av[4], bv[4];
    #pragma unroll
    for (int i = 0; i < 4; ++i) {
      av[i] = *(const float4*)(aptr + (size_t)(i * 32) * NN + k0);
      bv[i] = *(const float4*)(bptr + (size_t)(i * 32) * NN + k0);
    }
    if (sg) {
      #pragma unroll
      for (int i = 0; i < 4; ++i) {
        av[i].x = sigm(av[i].x); av[i].y = sigm(av[i].y); av[i].z = sigm(av[i].z); av[i].w = sigm(av[i].w);
        bv[i].x = sigm(bv[i].x); bv[i].y = sigm(bv[i].y); bv[i].z = sigm(bv[i].z); bv[i].w = sigm(bv[i].w);
      }
    }
    __syncthreads();                  // previous iteration's reads done
    #pragma unroll
    for (int i = 0; i < 4; ++i) {
      int r = sr + i * 32;
      As[LADDR(sc + 0, r)] = av[i].x; As[LADDR(sc + 1, r)] = av[i].y;
      As[LADDR(sc + 2, r)] = av[i].z; As[LADDR(sc + 3, r)] = av[i].w;
      Bs[LADDR(sc + 0, r)] = bv[i].x; Bs[LADDR(sc + 1, r)] = bv[i].y;
      Bs[LADDR(sc + 2, r)] = bv[i].z; Bs[LADDR(sc + 3, r)] = bv[i].w;
    }
    __syncthreads();
    #pragma unroll
    for (int kk = 0; kk < 32; ++kk) {
      float4 a0 = *(const float4*)&As[kk * LST + aoff];
      float4 a1 = *(const float4*)&As[kk * LST + aoff + 4];
      float4 b0 = *(const float4*)&Bs[kk * LST + boff];
      float4 b1 = *(const float4*)&Bs[kk * LST + boff + 4];
      float a[8] = {a0.x, a0.y, a0.z, a0.w, a1.x, a1.y, a1.z, a1.w};
      float b[8] = {b0.x, b0.y, b0.z, b0.w, b1.x, b1.y, b1.z, b1.w};
      #pragma unroll
      for (int r = 0; r < 8; ++r)
        #pragma unroll
        for (int c = 0; c < 8; ++c)
          acc[r][c] = fmaf(a[r], b[c], acc[r][c]);
    }
  }

  const float* sqm = sq + (size_t)m * NN;
  float sqi[8], sqj[8];
  #pragma unroll
  for (int r = 0; r < 8; ++r) sqi[r] = sqm[by * 128 + ty * 8 + r];
  #pragma unroll
  for (int c = 0; c < 8; ++c) sqj[c] = sqm[bx * 128 + tx * 8 + c];

  float tmax = 0.f;
  #pragma unroll
  for (int r = 0; r < 8; ++r) {
    #pragma unroll
    for (int c = 0; c < 8; ++c) {
      float v = sqrtf(fmaxf(sqi[r] + sqj[c] - 2.f * acc[r][c], 0.f));
      acc[r][c] = v;
      tmax = fmaxf(tmax, v);
    }
  }

  float* Dm = Dreg + (size_t)mL * NN2;
  int gr0 = by * 128 + ty * 8, gc0 = bx * 128 + tx * 8;
  #pragma unroll
  for (int r = 0; r < 8; ++r) {
    float4 o0 = make_float4(acc[r][0], acc[r][1], acc[r][2], acc[r][3]);
    float4 o1 = make_float4(acc[r][4], acc[r][5], acc[r][6], acc[r][7]);
    *(float4*)(Dm + (size_t)(gr0 + r) * NN + gc0) = o0;
    *(float4*)(Dm + (size_t)(gr0 + r) * NN + gc0 + 4) = o1;
  }
  if (by != bx) {
    #pragma unroll
    for (int c = 0; c < 8; ++c) {
      float4 o0 = make_float4(acc[0][c], acc[1][c], acc[2][c], acc[3][c]);
      float4 o1 = make_float4(acc[4][c], acc[5][c], acc[6][c], acc[7][c]);
      *(float4*)(Dm + (size_t)(gc0 + c) * NN + gr0) = o0;
      *(float4*)(Dm + (size_t)(gc0 + c) * NN + gr0 + 4) = o1;
    }
  }
  #pragma unroll
  for (int off = 32; off > 0; off >>= 1) tmax = fmaxf(tmax, __shfl_down(tmax, off));
  if ((tid & 63) == 0) atomicMax(&maxBits[m], __float_as_uint(tmax));
}

// ---------------- Boruvka MST: 1 block (1024 thr) per matrix --------------------
// Key = (f32 distance bits << 32) | canonical pair id (min*512+max).
// Global total order on keys => hooking graph has only mutual 2-cycles, and
// mutual components always agree on the SAME edge. Edge set == unique MST ==
// Prim's edge set for distinct weights (exact-tie swaps change loss ~1e-3).
__global__ __launch_bounds__(1024) void boruvka_kernel(const float* __restrict__ Dreg,
                                                       int2* __restrict__ edges, int m0) {
  int mL = blockIdx.x;
  int m = m0 + mL;
  const float* D = Dreg + (size_t)mL * NN2;
  int2* eo = edges + (size_t)m * (NN - 1);

  __shared__ int comp[NN];
  __shared__ unsigned long long best[NN];
  __shared__ int hook[NN];
  __shared__ int parent[NN];
  __shared__ int ecnt;

  int tid = threadIdx.x;
  int r = tid & 511;            // row handled by this thread
  int half = tid >> 9;          // 0: cols 0..255, 1: cols 256..511

  if (tid < NN) comp[tid] = tid;
  if (tid == 0) ecnt = 0;
  __syncthreads();

  for (int ph = 0; ph < 9; ++ph) {
    int ec = ecnt;
    if (ec >= NN - 1) break;

    if (tid < NN) best[tid] = ~0ull;
    __syncthreads();

    // ---- scan: each thread min-reduces half a row with component filter
    int cr = comp[r];
    const float4* rp = (const float4*)(D + (size_t)r * NN + half * 256);
    const int4* cp = (const int4*)(comp + half * 256);
    unsigned long long k = ~0ull;
    int cbase = half * 256;
    #pragma unroll 4
    for (int q = 0; q < 64; ++q) {
      float4 v = rp[q];
      int4 cc = cp[q];
      int c0 = cbase + q * 4;
      if (cc.x != cr) {
        int lo = (r < c0+0) ? r * NN + (c0+0) : (c0+0) * NN + r;
        unsigned long long key = ((unsigned long long)__float_as_uint(v.x) << 32) | (unsigned)lo;
        if (key < k) k = key;
      }
      if (cc.y != cr) {
        int lo = (r < c0+1) ? r * NN + (c0+1) : (c0+1) * NN + r;
        unsigned long long key = ((unsigned long long)__float_as_uint(v.y) << 32) | (unsigned)lo;
        if (key < k) k = key;
      }
      if (cc.z != cr) {
        int lo = (r < c0+2) ? r * NN + (c0+2) : (c0+2) * NN + r;
        unsigned long long key = ((unsigned long long)__float_as_uint(v.z) << 32) | (unsigned)lo;
        if (key < k) k = key;
      }
      if (cc.w != cr) {
        int lo = (r < c0+3) ? r * NN + (c0+3) : (c0+3) * NN + r;
        unsigned long long key = ((unsigned long long)__float_as_uint(v.w) << 32) | (unsigned)lo;
        if (key < k) k = key;
      }
    }
    if (k != ~0ull) amin64(&best[cr], k);
    __syncthreads();

    // ---- hook: component -> component of best edge's other endpoint
    if (tid < NN) {
      unsigned long long b = best[tid];
      if (b != ~0ull) {
        int idx = (int)(unsigned)b;
        int er = idx >> 9, ecc = idx & 511;
        int c1 = comp[er], c2 = comp[ecc];
        hook[tid] = (c1 == tid) ? c2 : c1;
      } else {
        hook[tid] = tid;
      }
    }
    __syncthreads();

    // ---- break mutual 2-cycles, emit edges
    if (tid < NN) {
      unsigned long long b = best[tid];
      bool active = (b != ~0ull);
      int p = hook[tid];
      bool mutual = active && (hook[p] == tid);
      parent[tid] = (!active) ? tid : ((mutual && tid < p) ? tid : p);
      if (active && (!mutual || tid > p)) {
        int idx = (int)(unsigned)b;
        int e = atomicAdd(&ecnt, 1);
        eo[e] = make_int2(idx >> 9, idx & 511);
      }
    }
    __syncthreads();

    // ---- relabel: chase to root (parent[] is read-only now; only 2-cycles
    // existed and were broken, so chains terminate at roots)
    if (tid < NN) {
      int c = comp[tid];
      int pp = parent[c];
      while (pp != c) { c = pp; pp = parent[c]; }
      comp[tid] = c;
    }
    __syncthreads();
  }
}

// ---------------- gather loss over MST edges (one block per matrix) -------------
__global__ __launch_bounds__(256) void gather_kernel(const float* __restrict__ Dreg,
                                                     const unsigned* __restrict__ maxBits,
                                                     const int2* __restrict__ edges,
                                                     float* __restrict__ out,
                                                     int m0) {
  int lm = blockIdx.x;
  int m = m0 + lm;
  int b = m >> 1;
  int lb = lm >> 1;
  float mxX = fmaxf(__uint_as_float(maxBits[2 * b]), 1e-12f);
  float mxZ = fmaxf(__uint_as_float(maxBits[2 * b + 1]), 1e-12f);
  float rX = 1.0f / mxX, rZ = 1.0f / mxZ;
  const float* Dx = Dreg + (size_t)(2 * lb) * NN2;
  const float* Dz = Dreg + (size_t)(2 * lb + 1) * NN2;
  const int2* eo = edges + (size_t)m * (NN - 1);
  float acc = 0.f;
  for (int s = threadIdx.x; s < NN - 1; s += 256) {
    int2 e = eo[s];
    size_t off = (size_t)e.x * NN + e.y;
    float d = Dx[off] * rX - Dz[off] * rZ;
    acc += d * d;
  }
  __shared__ float red[256];
  red[threadIdx.x] = acc;
  __syncthreads();
  for (int h = 128; h > 0; h >>= 1) {
    if (threadIdx.x < h) red[threadIdx.x] += red[threadIdx.x + h];
    __syncthreads();
  }
  if (threadIdx.x == 0) atomicAdd(out, red[0] * (1.0f / NB));
}

extern "C" void kernel_launch(void* const* d_in, const int* in_sizes, int n_in,
                              void* d_out, int out_size, void* d_ws, size_t ws_size,
                              hipStream_t stream) {
  const float* model = (const float*)d_in[0];
  const float* labels = (const float*)d_in[1];
  float* out = (float*)d_out;
  char* ws = (char*)d_ws;

  float*    sq      = (float*)(ws);             // 64*512 f32  = 131072 B
  unsigned* maxBits = (unsigned*)(ws + 131072); // 64 u32
  int2*     edges   = (int2*)(ws + 132096);     // 64*511 int2 = 261632 B
  float*    Dreg    = (float*)(ws + 524288);    // chunked D matrices, 1 MB each

  size_t dcap = (ws_size > 524288) ? (ws_size - 524288) : 0;
  int cb = (int)(dcap / (2ull * sizeof(float) * NN2));
  if (cb > NB) cb = NB;
  if (cb < 1) cb = 1;

  hipMemsetAsync(d_out, 0, sizeof(float), stream);
  hipMemsetAsync(maxBits, 0, 64 * sizeof(unsigned), stream);
  sq_kernel<<<8192, 256, 0, stream>>>(model, labels, sq);

  for (int b0 = 0; b0 < NB; b0 += cb) {
    int nb = (NB - b0 < cb) ? (NB - b0) : cb;
    int nm = 2 * nb, m0 = 2 * b0;
    gemm_dist<<<dim3(10, nm), 256, 0, stream>>>(model, labels, sq, Dreg, maxBits, m0);
    boruvka_kernel<<<nm, 1024, 0, stream>>>(Dreg, edges, m0);
    gather_kernel<<<nm, 256, 0, stream>>>(Dreg, maxBits, edges, out, m0);
  }
}

// Round 5
// 332.912 us; speedup vs baseline: 2.9527x; 1.6148x over previous
//
#include <hip/hip_runtime.h>
#include <math.h>

#define NN 512
#define NN2 (NN*NN)
#define NB 32
#define NM 64
#define FLTMAX 3.402823466e38f
#define LDH 40      // LDS row stride in bf16 units (80B: 16B-aligned, uniform 2-way banks)

typedef __attribute__((ext_vector_type(8))) short short8v;   // 8 bf16 (4 VGPR)
typedef __attribute__((ext_vector_type(4))) float f32x4;     // MFMA acc

__device__ __forceinline__ float sigm(float x) { return 1.0f / (1.0f + expf(-x)); }

__device__ __forceinline__ unsigned short f2bf(float x) {
  unsigned u = __float_as_uint(x);
  return (unsigned short)((u + 0x7fffu + ((u >> 16) & 1u)) >> 16);   // RNE
}
__device__ __forceinline__ float bf2f(unsigned short h) {
  return __uint_as_float(((unsigned)h) << 16);
}

// u64 atomic-min on LDS via CAS loop
__device__ __forceinline__ void amin64(unsigned long long* p, unsigned long long v) {
  unsigned long long old = *p;
  while (v < old) {
    unsigned long long assumed = old;
    old = atomicCAS(p, assumed, v);
    if (old == assumed) break;
  }
}

// ---------------- row sums of squares (fp32 exact, with sigmoid) ----------------
__global__ __launch_bounds__(256) void sq_kernel(const float* __restrict__ model,
                                                 const float* __restrict__ labels,
                                                 float* __restrict__ sq) {
  int gw = blockIdx.x * 4 + (threadIdx.x >> 6);
  int lane = threadIdx.x & 63;
  int m = gw >> 9;
  int row = gw & 511;
  if (m >= NM) return;
  const float* src = (m & 1) ? labels + (size_t)(m >> 1) * NN2
                             : model + (size_t)(m >> 1) * NN2;
  bool sg = !(m & 1);
  const float4* rp = (const float4*)(src + (size_t)row * NN);
  float s = 0.f;
  #pragma unroll
  for (int c = 0; c < 2; ++c) {
    float4 v = rp[lane + c * 64];
    if (sg) { v.x = sigm(v.x); v.y = sigm(v.y); v.z = sigm(v.z); v.w = sigm(v.w); }
    s += v.x * v.x + v.y * v.y + v.z * v.z + v.w * v.w;
  }
  #pragma unroll
  for (int off = 32; off > 0; off >>= 1) s += __shfl_down(s, off);
  if (lane == 0) sq[(size_t)m * NN + row] = s;
}

// ---------------- sigmoid + bf16 hi/lo split (once per matrix) ------------------
__global__ __launch_bounds__(256) void split_kernel(const float* __restrict__ model,
                                                    const float* __restrict__ labels,
                                                    unsigned short* __restrict__ Hi,
                                                    unsigned short* __restrict__ Lo,
                                                    int m0) {
  int b = blockIdx.x;
  int mL = b >> 8;
  int m = m0 + mL;
  size_t off = (size_t)(b & 255) * 1024 + threadIdx.x * 4;
  const float* src = ((m & 1) ? labels + (size_t)(m >> 1) * NN2
                              : model + (size_t)(m >> 1) * NN2) + off;
  float4 v = *(const float4*)src;
  if (!(m & 1)) { v.x = sigm(v.x); v.y = sigm(v.y); v.z = sigm(v.z); v.w = sigm(v.w); }
  ushort4 h, l;
  h.x = f2bf(v.x); l.x = f2bf(v.x - bf2f(h.x));
  h.y = f2bf(v.y); l.y = f2bf(v.y - bf2f(h.y));
  h.z = f2bf(v.z); l.z = f2bf(v.z - bf2f(h.z));
  h.w = f2bf(v.w); l.w = f2bf(v.w - bf2f(h.w));
  *(ushort4*)(Hi + (size_t)mL * NN2 + off) = h;
  *(ushort4*)(Lo + (size_t)mL * NN2 + off) = l;
}

// ------- distance matrix via 3-pass split-bf16 MFMA; triangle + mirror ----------
__global__ __launch_bounds__(256) void gemm_dist(const unsigned short* __restrict__ Hi,
                                                 const unsigned short* __restrict__ Lo,
                                                 const float* __restrict__ sq,
                                                 float* __restrict__ Dreg,
                                                 unsigned* __restrict__ maxBits, int m0) {
  __shared__ unsigned short Ah[128 * LDH], Al[128 * LDH];
  __shared__ unsigned short Bh[128 * LDH], Bl[128 * LDH];
  int p = blockIdx.x;                 // 0..9 upper-triangle pair of 128-panels
  int by = (p >= 4) + (p >= 7) + (p >= 9);
  int bx = p - ((by * (7 - by)) >> 1);
  bool diag = (by == bx);
  int mL = blockIdx.y;
  int m = m0 + mL;
  const unsigned short* Hm = Hi + (size_t)mL * NN2;
  const unsigned short* Lm = Lo + (size_t)mL * NN2;

  int tid = threadIdx.x;
  int wid = tid >> 6, lane = tid & 63;
  int wy = wid >> 1, wx = wid & 1;    // 2x2 waves of 64x64
  int lr = lane & 15, lk = lane >> 4;
  int trow = tid >> 1, tseg = tid & 1;  // staging: row 0..127, 16-bf16 segment

  f32x4 acc[4][4];
  #pragma unroll
  for (int i = 0; i < 4; ++i)
    #pragma unroll
    for (int j = 0; j < 4; ++j) acc[i][j] = (f32x4){0.f, 0.f, 0.f, 0.f};

  const unsigned short* gAh = Hm + (size_t)(by * 128 + trow) * NN + tseg * 16;
  const unsigned short* gAl = Lm + (size_t)(by * 128 + trow) * NN + tseg * 16;
  const unsigned short* gBh = Hm + (size_t)(bx * 128 + trow) * NN + tseg * 16;
  const unsigned short* gBl = Lm + (size_t)(bx * 128 + trow) * NN + tseg * 16;
  unsigned short* sAh = Ah + trow * LDH + tseg * 16;
  unsigned short* sAl = Al + trow * LDH + tseg * 16;
  unsigned short* sBh = Bh + trow * LDH + tseg * 16;
  unsigned short* sBl = Bl + trow * LDH + tseg * 16;

  const unsigned short* fAh = Ah + (wy * 64 + lr) * LDH + lk * 8;
  const unsigned short* fAl = Al + (wy * 64 + lr) * LDH + lk * 8;
  const unsigned short* fBh = (diag ? Ah : Bh) + (wx * 64 + lr) * LDH + lk * 8;
  const unsigned short* fBl = (diag ? Al : Bl) + (wx * 64 + lr) * LDH + lk * 8;

  for (int k0 = 0; k0 < NN; k0 += 32) {
    uint4 ah0 = *(const uint4*)(gAh + k0);
    uint4 ah1 = *(const uint4*)(gAh + k0 + 8);
    uint4 al0 = *(const uint4*)(gAl + k0);
    uint4 al1 = *(const uint4*)(gAl + k0 + 8);
    uint4 bh0, bh1, bl0, bl1;
    if (!diag) {
      bh0 = *(const uint4*)(gBh + k0);
      bh1 = *(const uint4*)(gBh + k0 + 8);
      bl0 = *(const uint4*)(gBl + k0);
      bl1 = *(const uint4*)(gBl + k0 + 8);
    }
    __syncthreads();                 // previous step's frag reads complete
    *(uint4*)(sAh) = ah0; *(uint4*)(sAh + 8) = ah1;
    *(uint4*)(sAl) = al0; *(uint4*)(sAl + 8) = al1;
    if (!diag) {
      *(uint4*)(sBh) = bh0; *(uint4*)(sBh + 8) = bh1;
      *(uint4*)(sBl) = bl0; *(uint4*)(sBl + 8) = bl1;
    }
    __syncthreads();

    short8v avh[4], avl[4], bvh[4], bvl[4];
    #pragma unroll
    for (int i = 0; i < 4; ++i) {
      avh[i] = *(const short8v*)(fAh + i * 16 * LDH);
      avl[i] = *(const short8v*)(fAl + i * 16 * LDH);
      bvh[i] = *(const short8v*)(fBh + i * 16 * LDH);
      bvl[i] = *(const short8v*)(fBl + i * 16 * LDH);
    }
    #pragma unroll
    for (int mi = 0; mi < 4; ++mi)
      #pragma unroll
      for (int ni = 0; ni < 4; ++ni)
        acc[mi][ni] = __builtin_amdgcn_mfma_f32_16x16x32_bf16(avh[mi], bvh[ni], acc[mi][ni], 0, 0, 0);
    #pragma unroll
    for (int mi = 0; mi < 4; ++mi)
      #pragma unroll
      for (int ni = 0; ni < 4; ++ni)
        acc[mi][ni] = __builtin_amdgcn_mfma_f32_16x16x32_bf16(avh[mi], bvl[ni], acc[mi][ni], 0, 0, 0);
    #pragma unroll
    for (int mi = 0; mi < 4; ++mi)
      #pragma unroll
      for (int ni = 0; ni < 4; ++ni)
        acc[mi][ni] = __builtin_amdgcn_mfma_f32_16x16x32_bf16(avl[mi], bvh[ni], acc[mi][ni], 0, 0, 0);
  }

  // epilogue: d = sqrt(max(sqi + sqj - 2*acc, 0)); write tile + mirror; fused max
  const float* sqm = sq + (size_t)m * NN;
  float* Dm = Dreg + (size_t)mL * NN2;
  int gr0 = by * 128 + wy * 64;
  int gc0 = bx * 128 + wx * 64;
  float tmax = 0.f;
  #pragma unroll
  for (int mi = 0; mi < 4; ++mi) {
    int rb = gr0 + mi * 16 + lk * 4;
    float sqi0 = sqm[rb + 0], sqi1 = sqm[rb + 1], sqi2 = sqm[rb + 2], sqi3 = sqm[rb + 3];
    #pragma unroll
    for (int ni = 0; ni < 4; ++ni) {
      int col = gc0 + ni * 16 + lr;
      float sqj = sqm[col];
      f32x4 a = acc[mi][ni];
      float v0 = sqrtf(fmaxf(sqi0 + sqj - 2.f * a[0], 0.f));
      float v1 = sqrtf(fmaxf(sqi1 + sqj - 2.f * a[1], 0.f));
      float v2 = sqrtf(fmaxf(sqi2 + sqj - 2.f * a[2], 0.f));
      float v3 = sqrtf(fmaxf(sqi3 + sqj - 2.f * a[3], 0.f));
      Dm[(size_t)(rb + 0) * NN + col] = v0;
      Dm[(size_t)(rb + 1) * NN + col] = v1;
      Dm[(size_t)(rb + 2) * NN + col] = v2;
      Dm[(size_t)(rb + 3) * NN + col] = v3;
      if (!diag)
        *(float4*)(Dm + (size_t)col * NN + rb) = make_float4(v0, v1, v2, v3);
      tmax = fmaxf(tmax, fmaxf(fmaxf(v0, v1), fmaxf(v2, v3)));
    }
  }
  #pragma unroll
  for (int off = 32; off > 0; off >>= 1) tmax = fmaxf(tmax, __shfl_down(tmax, off));
  if (lane == 0) atomicMax(&maxBits[m], __float_as_uint(tmax));
}

// ---------------- Boruvka MST: 2 full phases + LDS contraction ------------------
// Keys = (f32 bits << 32) | canonical pair id -> global total order (r4-validated).
__global__ __launch_bounds__(1024) void boruvka_kernel(const float* __restrict__ Dreg,
                                                       int2* __restrict__ edges, int m0) {
  int mL = blockIdx.x;
  int m = m0 + mL;
  const float* D = Dreg + (size_t)mL * NN2;
  int2* eo = edges + (size_t)m * (NN - 1);

  __shared__ unsigned long long Dc[128 * 128];  // contracted keys (128 KB)
  __shared__ int comp[NN];
  __shared__ unsigned long long best[NN];
  __shared__ int hook[NN];
  __shared__ int parent[NN];
  __shared__ int dmap[NN];
  __shared__ int comp2[128];
  __shared__ int ecnt, ccnt;

  int tid = threadIdx.x;
  int r = tid & 511, half = tid >> 9;
  int cbase = half * 256;

  if (tid < NN) comp[tid] = tid;
  if (tid == 0) { ecnt = 0; ccnt = 0; }
  __syncthreads();

  // ---- 2 full-matrix phases (guarantees <=128 components afterward)
  for (int ph = 0; ph < 2; ++ph) {
    if (tid < NN) best[tid] = ~0ull;
    __syncthreads();
    int cr = comp[r];
    const float4* rp = (const float4*)(D + (size_t)r * NN + cbase);
    unsigned long long k = ~0ull;
    #pragma unroll 4
    for (int q = 0; q < 64; ++q) {
      float4 v = rp[q];
      int4 cc = *(const int4*)(comp + cbase + q * 4);
      int c0 = cbase + q * 4;
      if (cc.x != cr) {
        int lo = (r < c0 + 0) ? r * NN + (c0 + 0) : (c0 + 0) * NN + r;
        unsigned long long key = ((unsigned long long)__float_as_uint(v.x) << 32) | (unsigned)lo;
        if (key < k) k = key;
      }
      if (cc.y != cr) {
        int lo = (r < c0 + 1) ? r * NN + (c0 + 1) : (c0 + 1) * NN + r;
        unsigned long long key = ((unsigned long long)__float_as_uint(v.y) << 32) | (unsigned)lo;
        if (key < k) k = key;
      }
      if (cc.z != cr) {
        int lo = (r < c0 + 2) ? r * NN + (c0 + 2) : (c0 + 2) * NN + r;
        unsigned long long key = ((unsigned long long)__float_as_uint(v.z) << 32) | (unsigned)lo;
        if (key < k) k = key;
      }
      if (cc.w != cr) {
        int lo = (r < c0 + 3) ? r * NN + (c0 + 3) : (c0 + 3) * NN + r;
        unsigned long long key = ((unsigned long long)__float_as_uint(v.w) << 32) | (unsigned)lo;
        if (key < k) k = key;
      }
    }
    if (k != ~0ull) amin64(&best[cr], k);
    __syncthreads();

    if (tid < NN) {
      unsigned long long b = best[tid];
      if (b != ~0ull) {
        int idx = (int)(unsigned)b;
        int er = idx >> 9, ec = idx & 511;
        int c1 = comp[er], c2 = comp[ec];
        hook[tid] = (c1 == tid) ? c2 : c1;
      } else hook[tid] = tid;
    }
    __syncthreads();
    if (tid < NN) {
      unsigned long long b = best[tid];
      bool active = (b != ~0ull);
      int pp = hook[tid];
      bool mutual = active && (hook[pp] == tid);
      parent[tid] = (!active) ? tid : ((mutual && tid < pp) ? tid : pp);
      if (active && (!mutual || tid > pp)) {
        int idx = (int)(unsigned)b;
        int e = atomicAdd(&ecnt, 1);
        eo[e] = make_int2(idx >> 9, idx & 511);
      }
    }
    __syncthreads();
    if (tid < NN) {
      int c = comp[tid];
      int pp = parent[c];
      while (pp != c) { c = pp; pp = parent[c]; }
      comp[tid] = c;
    }
    __syncthreads();
  }

  // ---- dense remap of surviving roots (C <= 128)
  if (tid < NN && comp[tid] == tid) dmap[tid] = atomicAdd(&ccnt, 1);
  __syncthreads();
  int C = ccnt;

  // ---- init + contraction scan (third and last full-matrix read)
  for (int i = tid; i < 128 * 128; i += 1024) Dc[i] = ~0ull;
  __syncthreads();
  {
    int cr = comp[r];
    int di = dmap[cr];
    const float4* rp = (const float4*)(D + (size_t)r * NN + cbase);
    #pragma unroll 4
    for (int q = 0; q < 64; ++q) {
      float4 v = rp[q];
      int4 cc = *(const int4*)(comp + cbase + q * 4);
      int c0 = cbase + q * 4;
      if (cc.x != cr) {
        int lo = (r < c0 + 0) ? r * NN + (c0 + 0) : (c0 + 0) * NN + r;
        amin64(&Dc[di * 128 + dmap[cc.x]],
               ((unsigned long long)__float_as_uint(v.x) << 32) | (unsigned)lo);
      }
      if (cc.y != cr) {
        int lo = (r < c0 + 1) ? r * NN + (c0 + 1) : (c0 + 1) * NN + r;
        amin64(&Dc[di * 128 + dmap[cc.y]],
               ((unsigned long long)__float_as_uint(v.y) << 32) | (unsigned)lo);
      }
      if (cc.z != cr) {
        int lo = (r < c0 + 2) ? r * NN + (c0 + 2) : (c0 + 2) * NN + r;
        amin64(&Dc[di * 128 + dmap[cc.z]],
               ((unsigned long long)__float_as_uint(v.z) << 32) | (unsigned)lo);
      }
      if (cc.w != cr) {
        int lo = (r < c0 + 3) ? r * NN + (c0 + 3) : (c0 + 3) * NN + r;
        amin64(&Dc[di * 128 + dmap[cc.w]],
               ((unsigned long long)__float_as_uint(v.w) << 32) | (unsigned)lo);
      }
    }
  }
  if (tid < 128) comp2[tid] = tid;
  __syncthreads();

  // ---- remaining phases entirely in LDS on the contracted matrix
  for (int ph = 0; ph < 7; ++ph) {
    if (ecnt >= NN - 1) break;
    if (tid < 128) best[tid] = ~0ull;
    __syncthreads();
    for (int i = tid; i < C * 128; i += 1024) {
      unsigned long long key = Dc[i];
      if (key == ~0ull) continue;
      int a = i >> 7, b = i & 127;
      int ca = comp2[a], cb2 = comp2[b];
      if (ca != cb2) amin64(&best[ca], key);
    }
    __syncthreads();
    if (tid < C) {
      unsigned long long b = best[tid];
      if (b != ~0ull) {
        int pid = (int)(unsigned)b;
        int er = pid >> 9, ec = pid & 511;
        int c1 = comp2[dmap[comp[er]]], c2 = comp2[dmap[comp[ec]]];
        hook[tid] = (c1 == tid) ? c2 : c1;
      } else hook[tid] = tid;
    }
    __syncthreads();
    if (tid < C) {
      unsigned long long b = best[tid];
      bool active = (b != ~0ull);
      int pp = hook[tid];
      bool mutual = active && (hook[pp] == tid);
      parent[tid] = (!active) ? tid : ((mutual && tid < pp) ? tid : pp);
      if (active && (!mutual || tid > pp)) {
        int pid = (int)(unsigned)b;
        int e = atomicAdd(&ecnt, 1);
        eo[e] = make_int2(pid >> 9, pid & 511);
      }
    }
    __syncthreads();
    if (tid < C) {
      int c = comp2[tid];
      int pp = parent[c];
      while (pp != c) { c = pp; pp = parent[c]; }
      comp2[tid] = c;
    }
    __syncthreads();
  }
}

// ---------------- gather loss over MST edges (one block per matrix) -------------
__global__ __launch_bounds__(256) void gather_kernel(const float* __restrict__ Dreg,
                                                     const unsigned* __restrict__ maxBits,
                                                     const int2* __restrict__ edges,
                                                     float* __restrict__ out,
                                                     int m0) {
  int lm = blockIdx.x;
  int m = m0 + lm;
  int b = m >> 1;
  int lb = lm >> 1;
  float mxX = fmaxf(__uint_as_float(maxBits[2 * b]), 1e-12f);
  float mxZ = fmaxf(__uint_as_float(maxBits[2 * b + 1]), 1e-12f);
  float rX = 1.0f / mxX, rZ = 1.0f / mxZ;
  const float* Dx = Dreg + (size_t)(2 * lb) * NN2;
  const float* Dz = Dreg + (size_t)(2 * lb + 1) * NN2;
  const int2* eo = edges + (size_t)m * (NN - 1);
  float acc = 0.f;
  for (int s = threadIdx.x; s < NN - 1; s += 256) {
    int2 e = eo[s];
    size_t off = (size_t)e.x * NN + e.y;
    float d = Dx[off] * rX - Dz[off] * rZ;
    acc += d * d;
  }
  __shared__ float red[256];
  red[threadIdx.x] = acc;
  __syncthreads();
  for (int h = 128; h > 0; h >>= 1) {
    if (threadIdx.x < h) red[threadIdx.x] += red[threadIdx.x + h];
    __syncthreads();
  }
  if (threadIdx.x == 0) atomicAdd(out, red[0] * (1.0f / NB));
}

extern "C" void kernel_launch(void* const* d_in, const int* in_sizes, int n_in,
                              void* d_out, int out_size, void* d_ws, size_t ws_size,
                              hipStream_t stream) {
  const float* model = (const float*)d_in[0];
  const float* labels = (const float*)d_in[1];
  float* out = (float*)d_out;
  char* ws = (char*)d_ws;

  float*    sq      = (float*)(ws);             // 131072 B
  unsigned* maxBits = (unsigned*)(ws + 131072); // 256 B
  int2*     edges   = (int2*)(ws + 132096);     // 261632 B
  size_t base = 524288;

  // per matrix: D (1MB fp32) + Hi (512KB bf16) + Lo (512KB bf16) = 2MB
  size_t dcap = (ws_size > base) ? (ws_size - base) : 0;
  int cb = (int)(dcap / (4ull * 1024 * 1024));   // batches (2 matrices) per chunk
  if (cb > NB) cb = NB;
  if (cb < 1) cb = 1;
  int nmc = 2 * cb;

  float* Dreg = (float*)(ws + base);
  unsigned short* Hi = (unsigned short*)(ws + base + (size_t)nmc * NN2 * sizeof(float));
  unsigned short* Lo = Hi + (size_t)nmc * NN2;

  hipMemsetAsync(d_out, 0, sizeof(float), stream);
  hipMemsetAsync(maxBits, 0, 64 * sizeof(unsigned), stream);
  sq_kernel<<<8192, 256, 0, stream>>>(model, labels, sq);

  for (int b0 = 0; b0 < NB; b0 += cb) {
    int nb = (NB - b0 < cb) ? (NB - b0) : cb;
    int nm = 2 * nb, m0 = 2 * b0;
    split_kernel<<<nm * 256, 256, 0, stream>>>(model, labels, Hi, Lo, m0);
    gemm_dist<<<dim3(10, nm), 256, 0, stream>>>(Hi, Lo, sq, Dreg, maxBits, m0);
    boruvka_kernel<<<nm, 1024, 0, stream>>>(Dreg, edges, m0);
    gather_kernel<<<nm, 256, 0, stream>>>(Dreg, maxBits, edges, out, m0);
  }
}

// Round 6
// 219.429 us; speedup vs baseline: 4.4798x; 1.5172x over previous
//
#include <hip/hip_runtime.h>
#include <math.h>

#define NN 512
#define NN2 (NN*NN)
#define NB 32
#define NM 64
#define FLTMAX 3.402823466e38f
#define LDH 40      // LDS row stride in bf16 units for gemm staging

typedef __attribute__((ext_vector_type(8))) short short8v;   // 8 bf16 (4 VGPR)
typedef __attribute__((ext_vector_type(4))) float f32x4;     // MFMA acc

__device__ __forceinline__ float sigm(float x) { return 1.0f / (1.0f + expf(-x)); }

__device__ __forceinline__ unsigned short f2bf(float x) {
  unsigned u = __float_as_uint(x);
  return (unsigned short)((u + 0x7fffu + ((u >> 16) & 1u)) >> 16);   // RNE
}
__device__ __forceinline__ float bf2f(unsigned short h) {
  return __uint_as_float(((unsigned)h) << 16);
}

// u64 atomic-min on LDS via CAS loop
__device__ __forceinline__ void amin64(unsigned long long* p, unsigned long long v) {
  unsigned long long old = *p;
  while (v < old) {
    unsigned long long assumed = old;
    old = atomicCAS(p, assumed, v);
    if (old == assumed) break;
  }
}

// DPP u64 min step: both halves routed identically, joint 64-bit compare.
template <int CTRL>
__device__ __forceinline__ unsigned long long dpp_min_u64(unsigned long long x) {
  int xlo = (int)(unsigned)x, xhi = (int)(unsigned)(x >> 32);
  int ylo = __builtin_amdgcn_update_dpp(xlo, xlo, CTRL, 0xf, 0xf, false);
  int yhi = __builtin_amdgcn_update_dpp(xhi, xhi, CTRL, 0xf, 0xf, false);
  unsigned long long y = ((unsigned long long)(unsigned)yhi << 32) | (unsigned)ylo;
  return (y < x) ? y : x;
}
// full wave u64 min -> valid in lane 63 (round-3-validated ctrl sequence)
__device__ __forceinline__ unsigned long long wave_min_u64(unsigned long long k) {
  k = dpp_min_u64<0x111>(k);
  k = dpp_min_u64<0x112>(k);
  k = dpp_min_u64<0x114>(k);
  k = dpp_min_u64<0x118>(k);
  k = dpp_min_u64<0x142>(k);
  k = dpp_min_u64<0x143>(k);
  return k;
}

// -------- sigmoid + bf16 hi/lo split + fused row sums-of-squares ----------------
__global__ __launch_bounds__(256) void split_kernel(const float* __restrict__ model,
                                                    const float* __restrict__ labels,
                                                    unsigned short* __restrict__ Hi,
                                                    unsigned short* __restrict__ Lo,
                                                    float* __restrict__ sq, int m0) {
  int b = blockIdx.x;
  int mL = b >> 8;
  int m = m0 + mL;
  int tid = threadIdx.x;
  size_t off = (size_t)(b & 255) * 1024 + tid * 4;
  const float* src = ((m & 1) ? labels + (size_t)(m >> 1) * NN2
                              : model + (size_t)(m >> 1) * NN2) + off;
  float4 v = *(const float4*)src;
  if (!(m & 1)) { v.x = sigm(v.x); v.y = sigm(v.y); v.z = sigm(v.z); v.w = sigm(v.w); }
  ushort4 h, l;
  h.x = f2bf(v.x); l.x = f2bf(v.x - bf2f(h.x));
  h.y = f2bf(v.y); l.y = f2bf(v.y - bf2f(h.y));
  h.z = f2bf(v.z); l.z = f2bf(v.z - bf2f(h.z));
  h.w = f2bf(v.w); l.w = f2bf(v.w - bf2f(h.w));
  *(ushort4*)(Hi + (size_t)mL * NN2 + off) = h;
  *(ushort4*)(Lo + (size_t)mL * NN2 + off) = l;
  // fused sq: block covers exactly 2 rows (waves 0,1 -> row0; waves 2,3 -> row1)
  float s = v.x * v.x + v.y * v.y + v.z * v.z + v.w * v.w;
  #pragma unroll
  for (int o = 32; o > 0; o >>= 1) s += __shfl_down(s, o);
  __shared__ float red[4];
  if ((tid & 63) == 0) red[tid >> 6] = s;
  __syncthreads();
  if (tid == 0) {
    int row0 = (b & 255) * 2;
    sq[(size_t)m * NN + row0]     = red[0] + red[1];
    sq[(size_t)m * NN + row0 + 1] = red[2] + red[3];
  }
}

// ------- distance matrix via 3-pass split-bf16 MFMA; triangle + mirror ----------
__global__ __launch_bounds__(256) void gemm_dist(const unsigned short* __restrict__ Hi,
                                                 const unsigned short* __restrict__ Lo,
                                                 const float* __restrict__ sq,
                                                 float* __restrict__ Dreg,
                                                 unsigned* __restrict__ maxBits, int m0) {
  __shared__ unsigned short Ah[128 * LDH], Al[128 * LDH];
  __shared__ unsigned short Bh[128 * LDH], Bl[128 * LDH];
  int p = blockIdx.x;                 // 0..9 upper-triangle pair of 128-panels
  int by = (p >= 4) + (p >= 7) + (p >= 9);
  int bx = p - ((by * (7 - by)) >> 1);
  bool diag = (by == bx);
  int mL = blockIdx.y;
  int m = m0 + mL;
  const unsigned short* Hm = Hi + (size_t)mL * NN2;
  const unsigned short* Lm = Lo + (size_t)mL * NN2;

  int tid = threadIdx.x;
  int wid = tid >> 6, lane = tid & 63;
  int wy = wid >> 1, wx = wid & 1;    // 2x2 waves of 64x64
  int lr = lane & 15, lk = lane >> 4;
  int trow = tid >> 1, tseg = tid & 1;  // staging: row 0..127, 16-bf16 segment

  f32x4 acc[4][4];
  #pragma unroll
  for (int i = 0; i < 4; ++i)
    #pragma unroll
    for (int j = 0; j < 4; ++j) acc[i][j] = (f32x4){0.f, 0.f, 0.f, 0.f};

  const unsigned short* gAh = Hm + (size_t)(by * 128 + trow) * NN + tseg * 16;
  const unsigned short* gAl = Lm + (size_t)(by * 128 + trow) * NN + tseg * 16;
  const unsigned short* gBh = Hm + (size_t)(bx * 128 + trow) * NN + tseg * 16;
  const unsigned short* gBl = Lm + (size_t)(bx * 128 + trow) * NN + tseg * 16;
  unsigned short* sAh = Ah + trow * LDH + tseg * 16;
  unsigned short* sAl = Al + trow * LDH + tseg * 16;
  unsigned short* sBh = Bh + trow * LDH + tseg * 16;
  unsigned short* sBl = Bl + trow * LDH + tseg * 16;

  const unsigned short* fAh = Ah + (wy * 64 + lr) * LDH + lk * 8;
  const unsigned short* fAl = Al + (wy * 64 + lr) * LDH + lk * 8;
  const unsigned short* fBh = (diag ? Ah : Bh) + (wx * 64 + lr) * LDH + lk * 8;
  const unsigned short* fBl = (diag ? Al : Bl) + (wx * 64 + lr) * LDH + lk * 8;

  for (int k0 = 0; k0 < NN; k0 += 32) {
    uint4 ah0 = *(const uint4*)(gAh + k0);
    uint4 ah1 = *(const uint4*)(gAh + k0 + 8);
    uint4 al0 = *(const uint4*)(gAl + k0);
    uint4 al1 = *(const uint4*)(gAl + k0 + 8);
    uint4 bh0, bh1, bl0, bl1;
    if (!diag) {
      bh0 = *(const uint4*)(gBh + k0);
      bh1 = *(const uint4*)(gBh + k0 + 8);
      bl0 = *(const uint4*)(gBl + k0);
      bl1 = *(const uint4*)(gBl + k0 + 8);
    }
    __syncthreads();
    *(uint4*)(sAh) = ah0; *(uint4*)(sAh + 8) = ah1;
    *(uint4*)(sAl) = al0; *(uint4*)(sAl + 8) = al1;
    if (!diag) {
      *(uint4*)(sBh) = bh0; *(uint4*)(sBh + 8) = bh1;
      *(uint4*)(sBl) = bl0; *(uint4*)(sBl + 8) = bl1;
    }
    __syncthreads();

    short8v avh[4], avl[4], bvh[4], bvl[4];
    #pragma unroll
    for (int i = 0; i < 4; ++i) {
      avh[i] = *(const short8v*)(fAh + i * 16 * LDH);
      avl[i] = *(const short8v*)(fAl + i * 16 * LDH);
      bvh[i] = *(const short8v*)(fBh + i * 16 * LDH);
      bvl[i] = *(const short8v*)(fBl + i * 16 * LDH);
    }
    #pragma unroll
    for (int mi = 0; mi < 4; ++mi)
      #pragma unroll
      for (int ni = 0; ni < 4; ++ni)
        acc[mi][ni] = __builtin_amdgcn_mfma_f32_16x16x32_bf16(avh[mi], bvh[ni], acc[mi][ni], 0, 0, 0);
    #pragma unroll
    for (int mi = 0; mi < 4; ++mi)
      #pragma unroll
      for (int ni = 0; ni < 4; ++ni)
        acc[mi][ni] = __builtin_amdgcn_mfma_f32_16x16x32_bf16(avh[mi], bvl[ni], acc[mi][ni], 0, 0, 0);
    #pragma unroll
    for (int mi = 0; mi < 4; ++mi)
      #pragma unroll
      for (int ni = 0; ni < 4; ++ni)
        acc[mi][ni] = __builtin_amdgcn_mfma_f32_16x16x32_bf16(avl[mi], bvh[ni], acc[mi][ni], 0, 0, 0);
  }

  const float* sqm = sq + (size_t)m * NN;
  float* Dm = Dreg + (size_t)mL * NN2;
  int gr0 = by * 128 + wy * 64;
  int gc0 = bx * 128 + wx * 64;
  float tmax = 0.f;
  #pragma unroll
  for (int mi = 0; mi < 4; ++mi) {
    int rb = gr0 + mi * 16 + lk * 4;
    float sqi0 = sqm[rb + 0], sqi1 = sqm[rb + 1], sqi2 = sqm[rb + 2], sqi3 = sqm[rb + 3];
    #pragma unroll
    for (int ni = 0; ni < 4; ++ni) {
      int col = gc0 + ni * 16 + lr;
      float sqj = sqm[col];
      f32x4 a = acc[mi][ni];
      float v0 = sqrtf(fmaxf(sqi0 + sqj - 2.f * a[0], 0.f));
      float v1 = sqrtf(fmaxf(sqi1 + sqj - 2.f * a[1], 0.f));
      float v2 = sqrtf(fmaxf(sqi2 + sqj - 2.f * a[2], 0.f));
      float v3 = sqrtf(fmaxf(sqi3 + sqj - 2.f * a[3], 0.f));
      Dm[(size_t)(rb + 0) * NN + col] = v0;
      Dm[(size_t)(rb + 1) * NN + col] = v1;
      Dm[(size_t)(rb + 2) * NN + col] = v2;
      Dm[(size_t)(rb + 3) * NN + col] = v3;
      if (!diag)
        *(float4*)(Dm + (size_t)col * NN + rb) = make_float4(v0, v1, v2, v3);
      tmax = fmaxf(tmax, fmaxf(fmaxf(v0, v1), fmaxf(v2, v3)));
    }
  }
  #pragma unroll
  for (int off = 32; off > 0; off >>= 1) tmax = fmaxf(tmax, __shfl_down(tmax, off));
  if (lane == 0) atomicMax(&maxBits[m], __float_as_uint(tmax));
}

// -------- Boruvka MST (coalesced wave-per-row scans) + fused loss gather --------
__global__ __launch_bounds__(1024) void boruvka_kernel(const float* __restrict__ Dreg,
                                                       const unsigned* __restrict__ maxBits,
                                                       float* __restrict__ out, int m0) {
  int mL = blockIdx.x;
  int m = m0 + mL;
  const float* D = Dreg + (size_t)mL * NN2;

  __shared__ unsigned long long Dc[128 * 128];  // contracted keys (128 KB)
  __shared__ int comp[NN];
  __shared__ int compP[NN + 64];                // padded copy: idx = i + (i>>3)
  __shared__ unsigned long long best[NN];
  __shared__ int hook[NN];
  __shared__ int parent[NN];
  __shared__ int dmap[NN];
  __shared__ int comp2[128];
  __shared__ int2 eL[NN - 1];
  __shared__ float fred[16];
  __shared__ int ecnt, ccnt;

  int tid = threadIdx.x;
  int wave = tid >> 6, lane = tid & 63;
  int c0 = lane * 8;

  if (tid < NN) { comp[tid] = tid; compP[tid + (tid >> 3)] = tid; }
  if (tid == 0) { ecnt = 0; ccnt = 0; }
  __syncthreads();

  // ---- 2 full-matrix phases, wave-per-row coalesced scans
  for (int ph = 0; ph < 2; ++ph) {
    if (tid < NN) best[tid] = ~0ull;
    __syncthreads();
    for (int rr = 0; rr < 32; ++rr) {
      int r = rr * 16 + wave;
      int cr = comp[r];                            // wave-uniform broadcast
      const float4* rp = (const float4*)(D + (size_t)r * NN + c0);
      float4 v0 = rp[0], v1 = rp[1];
      int4 cc0 = *(const int4*)(compP + c0 + (c0 >> 3));
      int4 cc1 = *(const int4*)(compP + c0 + 4 + (c0 >> 3));
      float vv[8] = {v0.x, v0.y, v0.z, v0.w, v1.x, v1.y, v1.z, v1.w};
      int cv[8] = {cc0.x, cc0.y, cc0.z, cc0.w, cc1.x, cc1.y, cc1.z, cc1.w};
      unsigned long long k = ~0ull;
      #pragma unroll
      for (int e = 0; e < 8; ++e) {
        if (cv[e] != cr) {
          int col = c0 + e;
          int lo = (r < col) ? r * NN + col : col * NN + r;
          unsigned long long key = ((unsigned long long)__float_as_uint(vv[e]) << 32) | (unsigned)lo;
          if (key < k) k = key;
        }
      }
      k = wave_min_u64(k);
      if (lane == 63 && k != ~0ull) amin64(&best[cr], k);
    }
    __syncthreads();

    if (tid < NN) {
      unsigned long long b = best[tid];
      if (b != ~0ull) {
        int idx = (int)(unsigned)b;
        int er = idx >> 9, ec = idx & 511;
        int c1 = comp[er], c2 = comp[ec];
        hook[tid] = (c1 == tid) ? c2 : c1;
      } else hook[tid] = tid;
    }
    __syncthreads();
    if (tid < NN) {
      unsigned long long b = best[tid];
      bool active = (b != ~0ull);
      int pp = hook[tid];
      bool mutual = active && (hook[pp] == tid);
      parent[tid] = (!active) ? tid : ((mutual && tid < pp) ? tid : pp);
      if (active && (!mutual || tid > pp)) {
        int idx = (int)(unsigned)b;
        int e = atomicAdd(&ecnt, 1);
        eL[e] = make_int2(idx >> 9, idx & 511);
      }
    }
    __syncthreads();
    if (tid < NN) {
      int c = comp[tid];
      int pp = parent[c];
      while (pp != c) { c = pp; pp = parent[c]; }
      comp[tid] = c;
      compP[tid + (tid >> 3)] = c;
    }
    __syncthreads();
  }

  // ---- dense remap of surviving roots (C <= 128)
  if (tid < NN && comp[tid] == tid) dmap[tid] = atomicAdd(&ccnt, 1);
  __syncthreads();
  int C = ccnt;

  // ---- Dc init + contraction scan (last full-matrix read), wave-per-row
  for (int i = tid; i < 128 * 128; i += 1024) Dc[i] = ~0ull;
  __syncthreads();
  for (int rr = 0; rr < 32; ++rr) {
    int r = rr * 16 + wave;
    int cr = comp[r];
    int di = dmap[cr];
    const float4* rp = (const float4*)(D + (size_t)r * NN + c0);
    float4 v0 = rp[0], v1 = rp[1];
    int4 cc0 = *(const int4*)(compP + c0 + (c0 >> 3));
    int4 cc1 = *(const int4*)(compP + c0 + 4 + (c0 >> 3));
    float vv[8] = {v0.x, v0.y, v0.z, v0.w, v1.x, v1.y, v1.z, v1.w};
    int cv[8] = {cc0.x, cc0.y, cc0.z, cc0.w, cc1.x, cc1.y, cc1.z, cc1.w};
    #pragma unroll
    for (int e = 0; e < 8; ++e) {
      if (cv[e] != cr) {
        int col = c0 + e;
        int lo = (r < col) ? r * NN + col : col * NN + r;
        unsigned long long key = ((unsigned long long)__float_as_uint(vv[e]) << 32) | (unsigned)lo;
        amin64(&Dc[di * 128 + dmap[cv[e]]], key);
      }
    }
  }
  if (tid < 128) comp2[tid] = tid;
  __syncthreads();

  // ---- remaining phases entirely in LDS on the contracted matrix
  for (int ph = 0; ph < 7; ++ph) {
    if (ecnt >= NN - 1) break;
    if (tid < 128) best[tid] = ~0ull;
    __syncthreads();
    for (int i = tid; i < C * 128; i += 1024) {
      unsigned long long key = Dc[i];
      if (key == ~0ull) continue;
      int a = i >> 7, b = i & 127;
      int ca = comp2[a], cb2 = comp2[b];
      if (ca != cb2) amin64(&best[ca], key);
    }
    __syncthreads();
    if (tid < C) {
      unsigned long long b = best[tid];
      if (b != ~0ull) {
        int pid = (int)(unsigned)b;
        int er = pid >> 9, ec = pid & 511;
        int c1 = comp2[dmap[comp[er]]], c2 = comp2[dmap[comp[ec]]];
        hook[tid] = (c1 == tid) ? c2 : c1;
      } else hook[tid] = tid;
    }
    __syncthreads();
    if (tid < C) {
      unsigned long long b = best[tid];
      bool active = (b != ~0ull);
      int pp = hook[tid];
      bool mutual = active && (hook[pp] == tid);
      parent[tid] = (!active) ? tid : ((mutual && tid < pp) ? tid : pp);
      if (active && (!mutual || tid > pp)) {
        int pid = (int)(unsigned)b;
        int e = atomicAdd(&ecnt, 1);
        eL[e] = make_int2(pid >> 9, pid & 511);
      }
    }
    __syncthreads();
    if (tid < C) {
      int c = comp2[tid];
      int pp = parent[c];
      while (pp != c) { c = pp; pp = parent[c]; }
      comp2[tid] = c;
    }
    __syncthreads();
  }
  __syncthreads();

  // ---- fused loss gather over this matrix's edge set
  int b = m >> 1;
  float mxX = fmaxf(__uint_as_float(maxBits[2 * b]), 1e-12f);
  float mxZ = fmaxf(__uint_as_float(maxBits[2 * b + 1]), 1e-12f);
  float rX = 1.0f / mxX, rZ = 1.0f / mxZ;
  const float* Dx = Dreg + (size_t)(mL & ~1) * NN2;
  const float* Dz = Dx + NN2;
  float acc = 0.f;
  if (tid < NN - 1) {
    int2 e = eL[tid];
    size_t off = (size_t)e.x * NN + e.y;
    float d = Dx[off] * rX - Dz[off] * rZ;
    acc = d * d;
  }
  #pragma unroll
  for (int o = 32; o > 0; o >>= 1) acc += __shfl_down(acc, o);
  if (lane == 0) fred[wave] = acc;
  __syncthreads();
  if (tid == 0) {
    float t = 0.f;
    #pragma unroll
    for (int i = 0; i < 16; ++i) t += fred[i];
    atomicAdd(out, t * (1.0f / NB));
  }
}

extern "C" void kernel_launch(void* const* d_in, const int* in_sizes, int n_in,
                              void* d_out, int out_size, void* d_ws, size_t ws_size,
                              hipStream_t stream) {
  const float* model = (const float*)d_in[0];
  const float* labels = (const float*)d_in[1];
  float* out = (float*)d_out;
  char* ws = (char*)d_ws;

  float*    sq      = (float*)(ws);             // 131072 B
  unsigned* maxBits = (unsigned*)(ws + 131072); // 256 B
  size_t base = 524288;

  // per matrix: D (1MB fp32) + Hi (512KB bf16) + Lo (512KB bf16) = 2MB
  size_t dcap = (ws_size > base) ? (ws_size - base) : 0;
  int cb = (int)(dcap / (4ull * 1024 * 1024));   // batches (2 matrices) per chunk
  if (cb > NB) cb = NB;
  if (cb < 1) cb = 1;
  int nmc = 2 * cb;

  float* Dreg = (float*)(ws + base);
  unsigned short* Hi = (unsigned short*)(ws + base + (size_t)nmc * NN2 * sizeof(float));
  unsigned short* Lo = Hi + (size_t)nmc * NN2;

  hipMemsetAsync(d_out, 0, sizeof(float), stream);
  hipMemsetAsync(maxBits, 0, 64 * sizeof(unsigned), stream);

  for (int b0 = 0; b0 < NB; b0 += cb) {
    int nb = (NB - b0 < cb) ? (NB - b0) : cb;
    int nm = 2 * nb, m0 = 2 * b0;
    split_kernel<<<nm * 256, 256, 0, stream>>>(model, labels, Hi, Lo, sq, m0);
    gemm_dist<<<dim3(10, nm), 256, 0, stream>>>(Hi, Lo, sq, Dreg, maxBits, m0);
    boruvka_kernel<<<nm, 1024, 0, stream>>>(Dreg, maxBits, out, m0);
  }
}

// Round 7
// 174.578 us; speedup vs baseline: 5.6307x; 1.2569x over previous
//
#include <hip/hip_runtime.h>
#include <math.h>

#define NN 512
#define NN2 (NN*NN)
#define NB 32
#define NM 64
#define LDH 40      // LDS row stride in bf16 units for gemm staging

typedef __attribute__((ext_vector_type(8))) short short8v;   // 8 bf16 (4 VGPR)
typedef __attribute__((ext_vector_type(4))) float f32x4;     // MFMA acc

__device__ __forceinline__ float sigm(float x) { return 1.0f / (1.0f + expf(-x)); }

__device__ __forceinline__ unsigned short f2bf(float x) {
  unsigned u = __float_as_uint(x);
  return (unsigned short)((u + 0x7fffu + ((u >> 16) & 1u)) >> 16);   // RNE
}
__device__ __forceinline__ float bf2f(unsigned short h) {
  return __uint_as_float(((unsigned)h) << 16);
}
__device__ __forceinline__ unsigned long long u64min(unsigned long long a,
                                                     unsigned long long b) {
  return (b < a) ? b : a;
}
// u64 atomic-min on LDS via CAS loop (proven r4-r6)
__device__ __forceinline__ void amin64(unsigned long long* p, unsigned long long v) {
  unsigned long long old = *p;
  while (v < old) {
    unsigned long long assumed = old;
    old = atomicCAS(p, assumed, v);
    if (old == assumed) break;
  }
}
template <int CTRL>
__device__ __forceinline__ unsigned long long dpp_min_u64(unsigned long long x) {
  int xlo = (int)(unsigned)x, xhi = (int)(unsigned)(x >> 32);
  int ylo = __builtin_amdgcn_update_dpp(xlo, xlo, CTRL, 0xf, 0xf, false);
  int yhi = __builtin_amdgcn_update_dpp(xhi, xhi, CTRL, 0xf, 0xf, false);
  unsigned long long y = ((unsigned long long)(unsigned)yhi << 32) | (unsigned)ylo;
  return (y < x) ? y : x;
}
// full wave u64 min -> valid in lane 63
__device__ __forceinline__ unsigned long long wave_min_u64(unsigned long long k) {
  k = dpp_min_u64<0x111>(k); k = dpp_min_u64<0x112>(k);
  k = dpp_min_u64<0x114>(k); k = dpp_min_u64<0x118>(k);
  k = dpp_min_u64<0x142>(k); k = dpp_min_u64<0x143>(k);
  return k;
}
// 16-lane-group u64 min -> valid in lane 15 of each group
__device__ __forceinline__ unsigned long long grp16_min_u64(unsigned long long k) {
  k = dpp_min_u64<0x111>(k); k = dpp_min_u64<0x112>(k);
  k = dpp_min_u64<0x114>(k); k = dpp_min_u64<0x118>(k);
  return k;
}

// -------- sigmoid + bf16 hi/lo split + fused row sums-of-squares ----------------
__global__ __launch_bounds__(256) void split_kernel(const float* __restrict__ model,
                                                    const float* __restrict__ labels,
                                                    unsigned short* __restrict__ Hi,
                                                    unsigned short* __restrict__ Lo,
                                                    float* __restrict__ sq, int m0) {
  int b = blockIdx.x;
  int mL = b >> 8;
  int m = m0 + mL;
  int tid = threadIdx.x;
  size_t off = (size_t)(b & 255) * 1024 + tid * 4;
  const float* src = ((m & 1) ? labels + (size_t)(m >> 1) * NN2
                              : model + (size_t)(m >> 1) * NN2) + off;
  float4 v = *(const float4*)src;
  if (!(m & 1)) { v.x = sigm(v.x); v.y = sigm(v.y); v.z = sigm(v.z); v.w = sigm(v.w); }
  ushort4 h, l;
  h.x = f2bf(v.x); l.x = f2bf(v.x - bf2f(h.x));
  h.y = f2bf(v.y); l.y = f2bf(v.y - bf2f(h.y));
  h.z = f2bf(v.z); l.z = f2bf(v.z - bf2f(h.z));
  h.w = f2bf(v.w); l.w = f2bf(v.w - bf2f(h.w));
  *(ushort4*)(Hi + (size_t)mL * NN2 + off) = h;
  *(ushort4*)(Lo + (size_t)mL * NN2 + off) = l;
  float s = v.x * v.x + v.y * v.y + v.z * v.z + v.w * v.w;
  #pragma unroll
  for (int o = 32; o > 0; o >>= 1) s += __shfl_down(s, o);
  __shared__ float red[4];
  if ((tid & 63) == 0) red[tid >> 6] = s;
  __syncthreads();
  if (tid == 0) {
    int row0 = (b & 255) * 2;
    sq[(size_t)m * NN + row0]     = red[0] + red[1];
    sq[(size_t)m * NN + row0 + 1] = red[2] + red[3];
  }
}

// ------- distance matrix via 3-pass split-bf16 MFMA + fused phase-1 argmin ------
__global__ __launch_bounds__(256) void gemm_dist(const unsigned short* __restrict__ Hi,
                                                 const unsigned short* __restrict__ Lo,
                                                 const float* __restrict__ sq,
                                                 float* __restrict__ Dreg,
                                                 unsigned* __restrict__ maxBits,
                                                 unsigned long long* __restrict__ best1,
                                                 int m0) {
  __shared__ unsigned short Ah[128 * LDH], Al[128 * LDH];
  __shared__ unsigned short Bh[128 * LDH], Bl[128 * LDH];
  int p = blockIdx.x;                 // 0..9 upper-triangle pair of 128-panels
  int by = (p >= 4) + (p >= 7) + (p >= 9);
  int bx = p - ((by * (7 - by)) >> 1);
  bool diag = (by == bx);
  int mL = blockIdx.y;
  int m = m0 + mL;
  const unsigned short* Hm = Hi + (size_t)mL * NN2;
  const unsigned short* Lm = Lo + (size_t)mL * NN2;

  int tid = threadIdx.x;
  int wid = tid >> 6, lane = tid & 63;
  int wy = wid >> 1, wx = wid & 1;    // 2x2 waves of 64x64
  int lr = lane & 15, lk = lane >> 4;
  int trow = tid >> 1, tseg = tid & 1;

  f32x4 acc[4][4];
  #pragma unroll
  for (int i = 0; i < 4; ++i)
    #pragma unroll
    for (int j = 0; j < 4; ++j) acc[i][j] = (f32x4){0.f, 0.f, 0.f, 0.f};

  const unsigned short* gAh = Hm + (size_t)(by * 128 + trow) * NN + tseg * 16;
  const unsigned short* gAl = Lm + (size_t)(by * 128 + trow) * NN + tseg * 16;
  const unsigned short* gBh = Hm + (size_t)(bx * 128 + trow) * NN + tseg * 16;
  const unsigned short* gBl = Lm + (size_t)(bx * 128 + trow) * NN + tseg * 16;
  unsigned short* sAh = Ah + trow * LDH + tseg * 16;
  unsigned short* sAl = Al + trow * LDH + tseg * 16;
  unsigned short* sBh = Bh + trow * LDH + tseg * 16;
  unsigned short* sBl = Bl + trow * LDH + tseg * 16;

  const unsigned short* fAh = Ah + (wy * 64 + lr) * LDH + lk * 8;
  const unsigned short* fAl = Al + (wy * 64 + lr) * LDH + lk * 8;
  const unsigned short* fBh = (diag ? Ah : Bh) + (wx * 64 + lr) * LDH + lk * 8;
  const unsigned short* fBl = (diag ? Al : Bl) + (wx * 64 + lr) * LDH + lk * 8;

  for (int k0 = 0; k0 < NN; k0 += 32) {
    uint4 ah0 = *(const uint4*)(gAh + k0);
    uint4 ah1 = *(const uint4*)(gAh + k0 + 8);
    uint4 al0 = *(const uint4*)(gAl + k0);
    uint4 al1 = *(const uint4*)(gAl + k0 + 8);
    uint4 bh0, bh1, bl0, bl1;
    if (!diag) {
      bh0 = *(const uint4*)(gBh + k0);
      bh1 = *(const uint4*)(gBh + k0 + 8);
      bl0 = *(const uint4*)(gBl + k0);
      bl1 = *(const uint4*)(gBl + k0 + 8);
    }
    __syncthreads();
    *(uint4*)(sAh) = ah0; *(uint4*)(sAh + 8) = ah1;
    *(uint4*)(sAl) = al0; *(uint4*)(sAl + 8) = al1;
    if (!diag) {
      *(uint4*)(sBh) = bh0; *(uint4*)(sBh + 8) = bh1;
      *(uint4*)(sBl) = bl0; *(uint4*)(sBl + 8) = bl1;
    }
    __syncthreads();

    short8v avh[4], avl[4], bvh[4], bvl[4];
    #pragma unroll
    for (int i = 0; i < 4; ++i) {
      avh[i] = *(const short8v*)(fAh + i * 16 * LDH);
      avl[i] = *(const short8v*)(fAl + i * 16 * LDH);
      bvh[i] = *(const short8v*)(fBh + i * 16 * LDH);
      bvl[i] = *(const short8v*)(fBl + i * 16 * LDH);
    }
    #pragma unroll
    for (int mi = 0; mi < 4; ++mi)
      #pragma unroll
      for (int ni = 0; ni < 4; ++ni)
        acc[mi][ni] = __builtin_amdgcn_mfma_f32_16x16x32_bf16(avh[mi], bvh[ni], acc[mi][ni], 0, 0, 0);
    #pragma unroll
    for (int mi = 0; mi < 4; ++mi)
      #pragma unroll
      for (int ni = 0; ni < 4; ++ni)
        acc[mi][ni] = __builtin_amdgcn_mfma_f32_16x16x32_bf16(avh[mi], bvl[ni], acc[mi][ni], 0, 0, 0);
    #pragma unroll
    for (int mi = 0; mi < 4; ++mi)
      #pragma unroll
      for (int ni = 0; ni < 4; ++ni)
        acc[mi][ni] = __builtin_amdgcn_mfma_f32_16x16x32_bf16(avl[mi], bvh[ni], acc[mi][ni], 0, 0, 0);
  }

  const float* sqm = sq + (size_t)m * NN;
  float* Dm = Dreg + (size_t)mL * NN2;
  int gr0 = by * 128 + wy * 64;
  int gc0 = bx * 128 + wx * 64;
  float tmax = 0.f;
  unsigned long long rk[4][4];        // per-(mi,reg) row-min keys
  unsigned long long ck[4];           // per-ni col-min keys (mirror side)
  #pragma unroll
  for (int i = 0; i < 4; ++i) {
    ck[i] = ~0ull;
    #pragma unroll
    for (int j = 0; j < 4; ++j) rk[i][j] = ~0ull;
  }
  #pragma unroll
  for (int mi = 0; mi < 4; ++mi) {
    int rb = gr0 + mi * 16 + lk * 4;
    float sqi0 = sqm[rb + 0], sqi1 = sqm[rb + 1], sqi2 = sqm[rb + 2], sqi3 = sqm[rb + 3];
    #pragma unroll
    for (int ni = 0; ni < 4; ++ni) {
      int col = gc0 + ni * 16 + lr;
      float sqj = sqm[col];
      f32x4 a = acc[mi][ni];
      float v0 = sqrtf(fmaxf(sqi0 + sqj - 2.f * a[0], 0.f));
      float v1 = sqrtf(fmaxf(sqi1 + sqj - 2.f * a[1], 0.f));
      float v2 = sqrtf(fmaxf(sqi2 + sqj - 2.f * a[2], 0.f));
      float v3 = sqrtf(fmaxf(sqi3 + sqj - 2.f * a[3], 0.f));
      Dm[(size_t)(rb + 0) * NN + col] = v0;
      Dm[(size_t)(rb + 1) * NN + col] = v1;
      Dm[(size_t)(rb + 2) * NN + col] = v2;
      Dm[(size_t)(rb + 3) * NN + col] = v3;
      if (!diag)
        *(float4*)(Dm + (size_t)col * NN + rb) = make_float4(v0, v1, v2, v3);
      tmax = fmaxf(tmax, fmaxf(fmaxf(v0, v1), fmaxf(v2, v3)));
      // fused phase-1 argmin keys (canonical pair id => r4-validated total order)
      float vv[4] = {v0, v1, v2, v3};
      #pragma unroll
      for (int rg = 0; rg < 4; ++rg) {
        int row = rb + rg;
        if (!diag || col != row) {
          unsigned lo = (row < col) ? (unsigned)(row * NN + col)
                                    : (unsigned)(col * NN + row);
          unsigned long long key =
              ((unsigned long long)__float_as_uint(vv[rg]) << 32) | lo;
          rk[mi][rg] = u64min(rk[mi][rg], key);
          ck[ni] = u64min(ck[ni], key);
        }
      }
    }
  }
  unsigned long long* b1 = best1 + (size_t)m * NN;
  #pragma unroll
  for (int mi = 0; mi < 4; ++mi)
    #pragma unroll
    for (int rg = 0; rg < 4; ++rg) {
      unsigned long long k = grp16_min_u64(rk[mi][rg]);
      if (lr == 15) atomicMin(&b1[gr0 + mi * 16 + lk * 4 + rg], k);
    }
  if (!diag) {
    #pragma unroll
    for (int ni = 0; ni < 4; ++ni) {
      unsigned long long k = ck[ni];
      k = u64min(k, __shfl_xor(k, 16));
      k = u64min(k, __shfl_xor(k, 32));
      if (lk == 0) atomicMin(&b1[gc0 + ni * 16 + lr], k);
    }
  }
  #pragma unroll
  for (int off = 32; off > 0; off >>= 1) tmax = fmaxf(tmax, __shfl_down(tmax, off));
  if (lane == 0) atomicMax(&maxBits[m], __float_as_uint(tmax));
}

// -------- phase-1 hook (comp = identity), emit edges, write comp labels ---------
__global__ __launch_bounds__(512) void hook1_kernel(const unsigned long long* __restrict__ best1,
                                                    int* __restrict__ compG,
                                                    int2* __restrict__ eo_all,
                                                    int* __restrict__ ecntG, int m0) {
  int mL = blockIdx.x, m = m0 + mL;
  const unsigned long long* b1 = best1 + (size_t)m * NN;
  int2* eo = eo_all + (size_t)m * (NN - 1);
  __shared__ int hook[NN], parent[NN];
  __shared__ int ecnt;
  int tid = threadIdx.x;
  if (tid == 0) ecnt = 0;
  unsigned long long b = b1[tid];
  int h;
  if (b != ~0ull) {
    int idx = (int)(unsigned)b;
    int er = idx >> 9, ec = idx & 511;
    h = (er == tid) ? ec : er;
  } else h = tid;
  hook[tid] = h;
  __syncthreads();
  bool active = (b != ~0ull);
  int p = h;
  bool mutual = active && (hook[p] == tid);
  parent[tid] = (!active) ? tid : ((mutual && tid < p) ? tid : p);
  if (active && (!mutual || tid > p)) {
    int idx = (int)(unsigned)b;
    int e = atomicAdd(&ecnt, 1);
    eo[e] = make_int2(idx >> 9, idx & 511);
  }
  __syncthreads();
  int c = tid, pp = parent[c];
  while (pp != c) { c = pp; pp = parent[c]; }
  compG[(size_t)m * NN + tid] = c;
  if (tid == 0) ecntG[m] = ecnt;
}

// -------- phase-2 scan: 8 blocks/matrix, wave-per-row, atomicMin per comp -------
__global__ __launch_bounds__(512) void scan2_kernel(const float* __restrict__ Dreg,
                                                    const int* __restrict__ compG,
                                                    unsigned long long* __restrict__ best2,
                                                    int m0) {
  int sblk = blockIdx.x, mL = blockIdx.y, m = m0 + mL;
  const float* D = Dreg + (size_t)mL * NN2;
  __shared__ int compP[NN + 64];
  int tid = threadIdx.x;
  int wave = tid >> 6, lane = tid & 63;
  int c0 = lane * 8;
  if (tid < NN) compP[tid + (tid >> 3)] = compG[(size_t)m * NN + tid];
  __syncthreads();
  unsigned long long* b2 = best2 + (size_t)m * NN;
  #pragma unroll
  for (int rr = 0; rr < 8; ++rr) {
    int r = sblk * 64 + wave * 8 + rr;
    int cr = compP[r + (r >> 3)];
    const float4* rp = (const float4*)(D + (size_t)r * NN + c0);
    float4 v0 = rp[0], v1 = rp[1];
    int4 cc0 = *(const int4*)(compP + c0 + (c0 >> 3));
    int4 cc1 = *(const int4*)(compP + c0 + 4 + (c0 >> 3));
    float vv[8] = {v0.x, v0.y, v0.z, v0.w, v1.x, v1.y, v1.z, v1.w};
    int cv[8] = {cc0.x, cc0.y, cc0.z, cc0.w, cc1.x, cc1.y, cc1.z, cc1.w};
    unsigned long long k = ~0ull;
    #pragma unroll
    for (int e = 0; e < 8; ++e) {
      if (cv[e] != cr) {
        int col = c0 + e;
        int lo = (r < col) ? r * NN + col : col * NN + r;
        unsigned long long key = ((unsigned long long)__float_as_uint(vv[e]) << 32) | (unsigned)lo;
        k = u64min(k, key);
      }
    }
    k = wave_min_u64(k);
    if (lane == 63 && k != ~0ull) atomicMin(&b2[cr], k);
  }
}

// -------- phase-2 hook + dense remap (C <= 128 guaranteed) ----------------------
__global__ __launch_bounds__(512) void hook2_kernel(const unsigned long long* __restrict__ best2,
                                                    const int* __restrict__ compG,
                                                    int* __restrict__ comp2g,
                                                    int2* __restrict__ eo_all,
                                                    int* __restrict__ ecntG,
                                                    int* __restrict__ cntG, int m0) {
  int mL = blockIdx.x, m = m0 + mL;
  const unsigned long long* b2 = best2 + (size_t)m * NN;
  int2* eo = eo_all + (size_t)m * (NN - 1);
  __shared__ int comp[NN], hook[NN], parent[NN], dmap[NN];
  __shared__ int ecnt, ccnt;
  int tid = threadIdx.x;
  if (tid == 0) { ecnt = ecntG[m]; ccnt = 0; }
  comp[tid] = compG[(size_t)m * NN + tid];
  __syncthreads();
  unsigned long long b = b2[tid];
  int h;
  if (b != ~0ull) {
    int idx = (int)(unsigned)b;
    int er = idx >> 9, ec = idx & 511;
    int c1 = comp[er], c2 = comp[ec];
    h = (c1 == tid) ? c2 : c1;
  } else h = tid;
  hook[tid] = h;
  __syncthreads();
  bool active = (b != ~0ull);
  int p = h;
  bool mutual = active && (hook[p] == tid);
  parent[tid] = (!active) ? tid : ((mutual && tid < p) ? tid : p);
  if (active && (!mutual || tid > p)) {
    int idx = (int)(unsigned)b;
    int e = atomicAdd(&ecnt, 1);
    eo[e] = make_int2(idx >> 9, idx & 511);
  }
  __syncthreads();
  int c = comp[tid], pp = parent[c];
  while (pp != c) { c = pp; pp = parent[c]; }
  __syncthreads();
  comp[tid] = c;
  __syncthreads();
  if (comp[tid] == tid) dmap[tid] = atomicAdd(&ccnt, 1);
  __syncthreads();
  comp2g[(size_t)m * NN + tid] = dmap[comp[tid]];
  if (tid == 0) { ecntG[m] = ecnt; cntG[m] = ccnt; }
}

// -------- contraction: 4 blocks/matrix build LDS-partial Dc, merge to global ----
__global__ __launch_bounds__(512) void contract_kernel(const float* __restrict__ Dreg,
                                                       const int* __restrict__ comp2g,
                                                       unsigned long long* __restrict__ DcG,
                                                       int m0) {
  int q = blockIdx.x, mL = blockIdx.y, m = m0 + mL;
  const float* D = Dreg + (size_t)mL * NN2;
  __shared__ unsigned long long Dc[128 * 128];
  __shared__ int c2P[NN + 64];
  int tid = threadIdx.x;
  int wave = tid >> 6, lane = tid & 63;
  int c0 = lane * 8;
  if (tid < NN) c2P[tid + (tid >> 3)] = comp2g[(size_t)m * NN + tid];
  for (int i = tid; i < 16384; i += 512) Dc[i] = ~0ull;
  __syncthreads();
  #pragma unroll
  for (int rr = 0; rr < 16; ++rr) {
    int r = q * 128 + wave * 16 + rr;
    int di = c2P[r + (r >> 3)];
    const float4* rp = (const float4*)(D + (size_t)r * NN + c0);
    float4 v0 = rp[0], v1 = rp[1];
    int4 cc0 = *(const int4*)(c2P + c0 + (c0 >> 3));
    int4 cc1 = *(const int4*)(c2P + c0 + 4 + (c0 >> 3));
    float vv[8] = {v0.x, v0.y, v0.z, v0.w, v1.x, v1.y, v1.z, v1.w};
    int cv[8] = {cc0.x, cc0.y, cc0.z, cc0.w, cc1.x, cc1.y, cc1.z, cc1.w};
    #pragma unroll
    for (int e = 0; e < 8; ++e) {
      if (cv[e] != di) {
        int col = c0 + e;
        int lo = (r < col) ? r * NN + col : col * NN + r;
        unsigned long long key = ((unsigned long long)__float_as_uint(vv[e]) << 32) | (unsigned)lo;
        amin64(&Dc[di * 128 + cv[e]], key);
      }
    }
  }
  __syncthreads();
  unsigned long long* dg = DcG + (size_t)mL * 16384;
  for (int i = tid; i < 16384; i += 512) {
    unsigned long long v = Dc[i];
    if (v != ~0ull) atomicMin(&dg[i], v);
  }
}

// -------- finish: LDS-resident phases on contracted matrix + fused gather -------
__global__ __launch_bounds__(1024) void finish_kernel(const float* __restrict__ Dreg,
                                                      const unsigned long long* __restrict__ DcG,
                                                      const int* __restrict__ comp2g,
                                                      const int* __restrict__ cntG,
                                                      int2* __restrict__ eo_all,
                                                      int* __restrict__ ecntG,
                                                      const unsigned* __restrict__ maxBits,
                                                      float* __restrict__ out, int m0) {
  int mL = blockIdx.x, m = m0 + mL;
  __shared__ unsigned long long Dc[16384];
  __shared__ int c2n[NN];
  __shared__ unsigned long long best[128];
  __shared__ int comp2[128], hook128[128], parent128[128];
  __shared__ float fred[16];
  __shared__ int ecnt;
  int tid = threadIdx.x;
  int wave = tid >> 6, lane = tid & 63;
  const unsigned long long* dg = DcG + (size_t)mL * 16384;
  for (int i = tid; i < 16384; i += 1024) Dc[i] = dg[i];
  if (tid < NN) c2n[tid] = comp2g[(size_t)m * NN + tid];
  if (tid < 128) comp2[tid] = tid;
  if (tid == 0) ecnt = ecntG[m];
  __syncthreads();
  int C = cntG[m];
  int2* eo = eo_all + (size_t)m * (NN - 1);

  for (int ph = 0; ph < 7; ++ph) {
    if (ecnt >= NN - 1) break;
    if (tid < 128) best[tid] = ~0ull;
    __syncthreads();
    for (int i = tid; i < C * 128; i += 1024) {
      unsigned long long key = Dc[i];
      if (key == ~0ull) continue;
      int a = i >> 7, bb = i & 127;
      int ca = comp2[a], cb = comp2[bb];
      if (ca != cb) amin64(&best[ca], key);
    }
    __syncthreads();
    if (tid < C) {
      unsigned long long b = best[tid];
      int h;
      if (b != ~0ull) {
        int pid = (int)(unsigned)b;
        int er = pid >> 9, ec = pid & 511;
        int c1 = comp2[c2n[er]], c2v = comp2[c2n[ec]];
        h = (c1 == tid) ? c2v : c1;
      } else h = tid;
      hook128[tid] = h;
    }
    __syncthreads();
    if (tid < C) {
      unsigned long long b = best[tid];
      bool active = (b != ~0ull);
      int p = hook128[tid];
      bool mutual = active && (hook128[p] == tid);
      parent128[tid] = (!active) ? tid : ((mutual && tid < p) ? tid : p);
      if (active && (!mutual || tid > p)) {
        int pid = (int)(unsigned)b;
        int e = atomicAdd(&ecnt, 1);
        eo[e] = make_int2(pid >> 9, pid & 511);
      }
    }
    __syncthreads();
    if (tid < C) {
      int c = comp2[tid], pp = parent128[c];
      while (pp != c) { c = pp; pp = parent128[c]; }
      comp2[tid] = c;
    }
    __syncthreads();
  }
  __syncthreads();

  // fused loss gather
  int b = m >> 1;
  float mxX = fmaxf(__uint_as_float(maxBits[2 * b]), 1e-12f);
  float mxZ = fmaxf(__uint_as_float(maxBits[2 * b + 1]), 1e-12f);
  float rX = 1.0f / mxX, rZ = 1.0f / mxZ;
  const float* Dx = Dreg + (size_t)(mL & ~1) * NN2;
  const float* Dz = Dx + NN2;
  float acc = 0.f;
  if (tid < NN - 1) {
    int2 e = eo[tid];
    size_t off = (size_t)e.x * NN + e.y;
    float d = Dx[off] * rX - Dz[off] * rZ;
    acc = d * d;
  }
  #pragma unroll
  for (int o = 32; o > 0; o >>= 1) acc += __shfl_down(acc, o);
  if (lane == 0) fred[wave] = acc;
  __syncthreads();
  if (tid == 0) {
    float t = 0.f;
    #pragma unroll
    for (int i = 0; i < 16; ++i) t += fred[i];
    atomicAdd(out, t * (1.0f / NB));
  }
}

extern "C" void kernel_launch(void* const* d_in, const int* in_sizes, int n_in,
                              void* d_out, int out_size, void* d_ws, size_t ws_size,
                              hipStream_t stream) {
  const float* model = (const float*)d_in[0];
  const float* labels = (const float*)d_in[1];
  float* out = (float*)d_out;
  char* ws = (char*)d_ws;

  float*              sq      = (float*)(ws);                       // 131072
  unsigned*           maxBits = (unsigned*)(ws + 131072);           // -> 132096
  int2*               eo      = (int2*)(ws + 132096);               // -> 393728
  unsigned long long* best1   = (unsigned long long*)(ws + 393728); // -> 655872
  unsigned long long* best2   = (unsigned long long*)(ws + 655872); // -> 918016
  int*                compG   = (int*)(ws + 918016);                // -> 1049088
  int*                comp2g  = (int*)(ws + 1049088);               // -> 1180160
  int*                ecntG   = (int*)(ws + 1180160);               // -> 1180416
  int*                cntG    = (int*)(ws + 1180416);               // -> 1180672
  size_t base = 1181696;

  // per batch (2 matrices): D 2MB + Hi 1MB + Lo 1MB = 4MB
  size_t dcap = (ws_size > base) ? (ws_size - base) : 0;
  int cb = (int)(dcap / (4ull * 1024 * 1024));
  if (cb > NB) cb = NB;
  if (cb < 1) cb = 1;
  int nmc = 2 * cb;

  float* Dreg = (float*)(ws + base);
  unsigned short* Hi = (unsigned short*)(ws + base + (size_t)nmc * NN2 * sizeof(float));
  unsigned short* Lo = Hi + (size_t)nmc * NN2;
  unsigned long long* DcG = (unsigned long long*)Hi;   // aliases Hi (dead post-gemm)

  hipMemsetAsync(d_out, 0, sizeof(float), stream);
  hipMemsetAsync(maxBits, 0, 64 * sizeof(unsigned), stream);

  for (int b0 = 0; b0 < NB; b0 += cb) {
    int nb = (NB - b0 < cb) ? (NB - b0) : cb;
    int nm = 2 * nb, m0 = 2 * b0;
    hipMemsetAsync(best1 + (size_t)m0 * NN, 0xFF, (size_t)nm * NN * 8, stream);
    hipMemsetAsync(best2 + (size_t)m0 * NN, 0xFF, (size_t)nm * NN * 8, stream);
    split_kernel<<<nm * 256, 256, 0, stream>>>(model, labels, Hi, Lo, sq, m0);
    gemm_dist<<<dim3(10, nm), 256, 0, stream>>>(Hi, Lo, sq, Dreg, maxBits, best1, m0);
    hipMemsetAsync(DcG, 0xFF, (size_t)nm * 16384 * 8, stream);   // after gemm (alias)
    hook1_kernel<<<nm, 512, 0, stream>>>(best1, compG, eo, ecntG, m0);
    scan2_kernel<<<dim3(8, nm), 512, 0, stream>>>(Dreg, compG, best2, m0);
    hook2_kernel<<<nm, 512, 0, stream>>>(best2, compG, comp2g, eo, ecntG, cntG, m0);
    contract_kernel<<<dim3(4, nm), 512, 0, stream>>>(Dreg, comp2g, DcG, m0);
    finish_kernel<<<nm, 1024, 0, stream>>>(Dreg, DcG, comp2g, cntG, eo, ecntG,
                                           maxBits, out, m0);
  }
}